// Round 11
// baseline (232.687 us; speedup 1.0000x reference)
//
#include <hip/hip_runtime.h>
#include <math.h>

#define Hh 80
#define Ww 80
#define HW 6400
#define PS 6724      // 82*82 padded spatial
#define NB 4

typedef _Float16 half8 __attribute__((ext_vector_type(8)));
typedef _Float16 half4v __attribute__((ext_vector_type(4)));
typedef float f32x16 __attribute__((ext_vector_type(16)));

// async global->LDS, 16B per lane. Dest is wave-uniform base (+lane*16 by HW);
// src is per-lane.
__device__ __forceinline__ void gload16(const _Float16* g, _Float16* l) {
    __builtin_amdgcn_global_load_lds(
        (const __attribute__((address_space(1))) void*)g,
        (__attribute__((address_space(3))) void*)l, 16, 0, 0);
}

// counted vmcnt wait (literal N) + full memory fence against code motion
#define WAITVM(N) asm volatile("s_waitcnt vmcnt(" #N ")" ::: "memory")
// issue-point pin: loads/stores cannot cross a memory clobber
#define FENCE() asm volatile("" ::: "memory")

__device__ __forceinline__ void barrier_mem() {
    asm volatile("" ::: "memory");
    __builtin_amdgcn_s_barrier();
    asm volatile("" ::: "memory");
}

// ---------------------------------------------------------------------------
// wblob helpers (weight-blob packing for MFMA A-operands)
// conv3x3 blob: flat = (CT*NS + c*18 + tap*2 + h)*512 + lane*8 + j
//   co = CT*32 + (lane&31);  ci = c*32 + h*16 + (lane>>5)*8 + j
// conv1x1 blob: flat = ((CT*8 + c)*64 + lane)*8 + j
//   co = CT*32 + (lane&31);  ci = c*16 + (lane>>5)*8 + j
// ---------------------------------------------------------------------------
__device__ inline void wblob_one(const float* src, _Float16* dst, int CI, int d) {
    int NC = CI / 32;
    int j = d & 7;
    int l = (d >> 3) & 63;
    int h = (d >> 9) & 1;
    int rest = d >> 10;
    int tap = rest % 9;
    rest /= 9;
    int c = rest % NC;
    int CT = rest / NC;
    int co = CT * 32 + (l & 31);
    int ci = c * 32 + h * 16 + (l >> 5) * 8 + j;
    dst[d] = (_Float16)src[((size_t)co * CI + ci) * 9 + tap];
}

__device__ inline void wblob1x1_one(const float* src, _Float16* dst, int d) {
    int j = d & 7;
    int l = (d >> 3) & 63;
    int c = (d >> 9) & 7;
    int CT = d >> 12;
    int co = CT * 32 + (l & 31);
    int ci = c * 16 + (l >> 5) * 8 + j;
    dst[d] = (_Float16)src[co * 128 + ci];
}

__device__ inline int padsite(int p) {
    if (p < 82) return p;                       // row 0
    if (p < 164) return 81 * 82 + (p - 82);     // row 81
    if (p < 244) return (p - 163) * 82;         // col 0, rows 1..80
    return (p - 243) * 82 + 81;                 // col 81, rows 1..80
}

// ---------------------------------------------------------------------------
// prep_all: fused {wblob prep + pad zeroing} U {q_transpose} U {v_transpose}.
// All three are mutually independent -> block-range dispatch, no interaction.
// b in [0,4304): prep; [4304,4704): q_transpose; [4704,5104): v_transpose.
// Both transpose offsets are multiples of 8 -> XCD pinning (b&7) preserved.
// (round-7 win: 3 launches -> 1, -4.6us)
// ---------------------------------------------------------------------------
__global__ __launch_bounds__(256) void prep_all(
    const float* __restrict__ w1, const float* __restrict__ w2,
    const float* __restrict__ w3, const float* __restrict__ w4,
    const float* __restrict__ vw, const float* __restrict__ ow,
    _Float16* __restrict__ b1, _Float16* __restrict__ b2,
    _Float16* __restrict__ b3, _Float16* __restrict__ b4,
    _Float16* __restrict__ bv, _Float16* __restrict__ bo,
    int* __restrict__ qh_i, int* __restrict__ hA_i, int* __restrict__ hB_i,
    const float* __restrict__ query, const float* __restrict__ value,
    _Float16* __restrict__ q_h, _Float16* __restrict__ v_h) {
    __shared__ _Float16 T[64 * 264];            // max(256+8, 128+8) stride tile
    const int blk = blockIdx.x;
    const int t = threadIdx.x;

    if (blk < 4304) {                           // ---- prep ----
        int idx = blk * 256 + t;
        if (idx < 294912) { wblob_one(w1, b1, 256, idx); return; }
        idx -= 294912;
        if (idx < 147456) { wblob_one(w2, b2, 128, idx); return; }
        idx -= 147456;
        if (idx < 147456) { wblob_one(w3, b3, 128, idx); return; }
        idx -= 147456;
        if (idx < 147456) { wblob_one(w4, b4, 128, idx); return; }
        idx -= 147456;
        if (idx < 16384) { wblob1x1_one(vw, bv, idx); return; }
        idx -= 16384;
        if (idx < 16384) { wblob1x1_one(ow, bo, idx); return; }
        idx -= 16384;
        if (idx < 165888) {  // q_h pads: 4n x 8c x 324 sites x 16 ints
            int n = idx / 41472, rr = idx % 41472;
            int c = rr / 5184, r2 = rr % 5184;
            int p = r2 >> 4, k = r2 & 15;
            qh_i[((size_t)(n * 8 + c) * PS + padsite(p)) * 16 + k] = 0;
            return;
        }
        idx -= 165888;
        if (idx < 82944) {   // hA pads
            int n = idx / 20736, rr = idx % 20736;
            int c = rr / 5184, r2 = rr % 5184;
            int p = r2 >> 4, k = r2 & 15;
            hA_i[((size_t)(n * 4 + c) * PS + padsite(p)) * 16 + k] = 0;
            return;
        }
        idx -= 82944;
        if (idx < 82944) {   // hB pads
            int n = idx / 20736, rr = idx % 20736;
            int c = rr / 5184, r2 = rr % 5184;
            int p = r2 >> 4, k = r2 & 15;
            hB_i[((size_t)(n * 4 + c) * PS + padsite(p)) * 16 + k] = 0;
        }
        return;
    }

    if (blk < 4704) {                           // ---- q_transpose ----
        const int b = blk - 4304;
        const int xcd = b & 7, n = xcd & 3, hi = xcd >> 2;
        const int s0 = hi * 3200 + (b >> 3) * 64;
        constexpr int CI = 256, ST = CI + 8;
        for (int idx = t; idx < 64 * CI; idx += 256) {
            int ci = idx >> 6, sl = idx & 63;
            T[sl * ST + ci] = (_Float16)query[((size_t)n * CI + ci) * HW + s0 + sl];
        }
        __syncthreads();
        for (int idx = t; idx < 64 * 32; idx += 256) {
            int q = idx & 31, sl = idx >> 5;
            int s = s0 + sl, yy = s / 80, xx = s % 80;
            int c = q >> 2, off = (q & 3) * 8;
            *(int4*)(q_h + ((size_t)(n * 8 + c) * PS + (yy + 1) * 82 + (xx + 1)) * 32 + off) =
                *(const int4*)(&T[sl * ST + q * 8]);
        }
        return;
    }

    {                                           // ---- v_transpose ----
        const int b = blk - 4704;
        const int xcd = b & 7, n = xcd & 3, hi = xcd >> 2;
        const int s0 = hi * 3200 + (b >> 3) * 64;
        constexpr int CI = 128, ST = CI + 8;
        for (int idx = t; idx < 64 * CI; idx += 256) {
            int ci = idx >> 6, sl = idx & 63;
            T[sl * ST + ci] = (_Float16)value[((size_t)n * CI + ci) * HW + s0 + sl];
        }
        __syncthreads();
        for (int idx = t; idx < 64 * 16; idx += 256) {
            int q = idx & 15, sl = idx >> 4;
            *(int4*)(v_h + ((size_t)n * HW + s0 + sl) * CI + q * 8) =
                *(const int4*)(&T[sl * ST + q * 8]);
        }
    }
}

// ---------------------------------------------------------------------------
// MFMA implicit-GEMM 3x3 conv, pad=1, chunked-planar fp16 in ([n][c][82x82][32]).
// v9 = v8 pipeline with the wave tile switched (1co x 2sp) -> (2co x 1sp):
// 4 waves = 2 co-pairs x 2 site-halves of the SAME 16x4 region. Per substep
// each wave now does ONE ds_read_b128 feeding TWO MFMAs (A from VGPRs) ->
// LDS port demand halves to 0.5 KB/MFMA (v8's 1.0 KB left the port 1.5-3x
// oversubscribed vs the ~85 B/cyc m134 ceiling). A-regs double: 4 x 6 half8
// dbuf = 96 VGPR; total ~170, under the (256,2) 256-cap (v7's spill was at
// the 128-cap -- WRITE_SIZE is the spill detector). Staging pattern, barrier
// structure (WAITVM now 24 = A-loads issued after each B-stage), K-order per
// acc, and outputs are unchanged -> bitwise-identical.
// ACT 1: leaky -> chunked-planar fp16 [n][4c][PS][32].
// ACT 2: 10*tanh -> fp32 NHWC [n][6400][128].
// ---------------------------------------------------------------------------
template <int NCp, int ACT>
__global__ __launch_bounds__(256, 2) void conv3x3_mfma(
    const _Float16* __restrict__ in, const _Float16* __restrict__ wblob,
    const float* __restrict__ bias, void* __restrict__ outp) {
    constexpr int NS = NCp * 18;
    static_assert((NCp & 1) == 0, "pair loop needs even NCp");
    __shared__ _Float16 Bbuf[2][6 * 1024];   // 2 x 12KB (B only)

    const int b = blockIdx.x;
    const int xcd = b & 7, n = xcd & 3, hi = xcd >> 2;
    const int r = b >> 3;                    // 0..49: 16x4 region
    const int x0 = (r % 5) * 16, y0 = hi * 40 + (r / 5) * 4;
    const int t = threadIdx.x;
    const int w = t >> 6, l = t & 63;
    const int coH = w & 1, sh = w >> 1;      // co-pair / site-half of wave
    const int lane31 = l & 31, lhalf = l >> 5;
    const int lx = lane31 & 15, lyw = lane31 >> 4;   // site col / row-in-half
    const int si = l & 15, g8 = l >> 4;      // staging: site / granule of lane

    const _Float16* bplane0 = in + (size_t)(n * NCp) * PS * 32;
    const _Float16* wA0 = wblob + (size_t)(2 * coH) * NS * 512 + l * 8;  // co-tile 2coH
    const _Float16* wA1 = wA0 + (size_t)NS * 512;                        // co-tile 2coH+1

    f32x16 acc0 = {}, acc1 = {};             // [co-tile 2coH, 2coH+1] x wave's 32 sites
    half8 a0A[6], a1A[6], a0B[6], a1B[6];    // per-group A register dbuf (2 co-tiles)

    // stage B-tile (6 rows x 2 segs) of a chunk plane into Bbuf[par] (3 loads/wave)
    auto stageB = [&](const _Float16* plane, int par) {
#pragma unroll
        for (int j = 0; j < 3; ++j) {
            const int m = 3 * w + j, rr = m >> 1, sg = m & 1;
            gload16(plane + ((size_t)((y0 + rr) * 82 + x0 + sg * 16 + si)) * 32 + g8 * 8,
                    &Bbuf[par][rr * 1024 + sg * 512]);
        }
    };
    // load the 12 A-frags (2 co-tiles x 6 substeps) of group grp into registers
    auto loadA12 = [&](half8 (&a0)[6], half8 (&a1)[6], int grp) {
        const _Float16* s0 = wA0 + (size_t)grp * 6 * 512;
        const _Float16* s1 = wA1 + (size_t)grp * 6 * 512;
#pragma unroll
        for (int k2 = 0; k2 < 6; ++k2) {
            a0[k2] = *(const half8*)(s0 + (size_t)k2 * 512);
            a1[k2] = *(const half8*)(s1 + (size_t)k2 * 512);
        }
    };
    // compute the 6 substeps of sub-group gi: 1 ds_read feeds 2 MFMAs
    auto compute6 = [&](int gi, const half8 (&a0)[6], const half8 (&a1)[6],
                        const _Float16* bb) {
#pragma unroll
        for (int k = 0; k < 6; ++k) {
            const int u = gi * 6 + k;            // compile-time after inline
            const int tap = u >> 1, h = u & 1;
            const int dy = tap / 3, dx = tap % 3;
            const int cx = lx + dx;
            const int boff = (cx >> 4) * 512 + (h * 2 + lhalf) * 128 + (cx & 15) * 8;
            half8 bv = *(const half8*)&bb[(2 * sh + lyw + dy) * 1024 + boff];
            acc0 = __builtin_amdgcn_mfma_f32_32x32x16_f16(a0[k], bv, acc0, 0, 0, 0);
            acc1 = __builtin_amdgcn_mfma_f32_32x32x16_f16(a1[k], bv, acc1, 0, 0, 0);
        }
    };

    // ---- prologue: B(chunk0) + A(group0), drained once ----
    stageB(bplane0, 0);
    loadA12(a0A, a1A, 0);
    WAITVM(0);
    barrier_mem();

#pragma unroll 1
    for (int cp = 0; cp < NCp / 2; ++cp) {
        const int c0 = 2 * cp;
        const bool lastp = (cp == NCp / 2 - 1);
        const _Float16* plane1 = bplane0 + (size_t)(c0 + 1) * PS * 32;
        const _Float16* plane2 = bplane0 + (size_t)(c0 + 2) * PS * 32;
        // g0: issue A(grp1)+B(c1), pin, compute grp0 from Bbuf0
        loadA12(a0B, a1B, c0 * 3 + 1);
        stageB(plane1, 1);
        FENCE();
        compute6(0, a0A, a1A, Bbuf[0]);
        // g1
        loadA12(a0A, a1A, c0 * 3 + 2);
        FENCE();
        compute6(1, a0B, a1B, Bbuf[0]);
        // g2: flip to Bbuf1 after this group
        loadA12(a0B, a1B, c0 * 3 + 3);
        FENCE();
        compute6(2, a0A, a1A, Bbuf[0]);
        WAITVM(24);          // B(c1) retired (24 A-loads issued after it)
        barrier_mem();       // all waves done reading Bbuf0; Bbuf1 visible
        // g3: stage next pair's even-chunk B into Bbuf0 (safe: post-barrier)
        loadA12(a0A, a1A, c0 * 3 + 4);
        if (!lastp) stageB(plane2, 0);
        FENCE();
        compute6(0, a0B, a1B, Bbuf[1]);
        // g4
        loadA12(a0B, a1B, c0 * 3 + 5);
        FENCE();
        compute6(1, a0A, a1A, Bbuf[1]);
        // g5: flip back to Bbuf0 (unless done)
        if (!lastp) {
            loadA12(a0A, a1A, c0 * 3 + 6);
            FENCE();
            compute6(2, a0B, a1B, Bbuf[1]);
            WAITVM(24);      // B(c0+2) retired (24 A-loads issued after it)
            barrier_mem();
        } else {
            FENCE();
            compute6(2, a0B, a1B, Bbuf[1]);
        }
    }

    // epilogue: D col(site)=lane&31 -> (y=y0+2sh+lyw, x=x0+lx);
    // row(co)=(reg&3)+8*(reg>>2)+4*(lane>>5); co-tile ct = 2coH+a
    const int x = x0 + lx;
    const int y = y0 + 2 * sh + lyw;
#pragma unroll
    for (int a = 0; a < 2; ++a) {
        const int ct = 2 * coH + a;
        const f32x16& acc = a ? acc1 : acc0;
#pragma unroll
        for (int q = 0; q < 4; ++q) {
            const int inner = 8 * q + 4 * lhalf;
            const int co0 = ct * 32 + inner;
            float v[4];
#pragma unroll
            for (int i = 0; i < 4; ++i) {
                float vv = acc[q * 4 + i] + bias[co0 + i];
                if (ACT == 1) vv = (vv >= 0.f) ? vv : 0.1f * vv;
                else vv = 10.f * tanhf(vv);
                v[i] = vv;
            }
            if (ACT == 1) {
                half4v hv = {(_Float16)v[0], (_Float16)v[1], (_Float16)v[2], (_Float16)v[3]};
                *(half4v*)((_Float16*)outp +
                    ((size_t)(n * 4 + ct) * PS + (y + 1) * 82 + (x + 1)) * 32 + inner) = hv;
            } else {
                float4 fv = {v[0], v[1], v[2], v[3]};
                *(float4*)((float*)outp + ((size_t)n * HW + y * 80 + x) * 128 + co0) = fv;
            }
        }
    }
}

// ---------------------------------------------------------------------------
// MFMA 1x1 conv (K=128), fp16 rows [n][s][128] in, fp32 out. Barrier-free,
// XCD-pinned. Block 256 = 4 waves x 32 sites; wave = 64co (2 co-tiles).
// All 24 loads issued before the 16 MFMAs. grid: flat (400).
// MODE 0: out v_s fp32 [n*8+hd][s][16].  MODE 1: out fp32 NCHW.
// ---------------------------------------------------------------------------
template <int MODE>
__global__ __launch_bounds__(256) void conv1x1_mfma(
    const _Float16* __restrict__ in, const _Float16* __restrict__ wblob,
    const float* __restrict__ bias, float* __restrict__ outp) {
    const int b = blockIdx.x;
    const int xcd = b & 7, n = xcd & 3, hi = xcd >> 2;
    const int r = b >> 3;                    // 0..49
    const int coH = r & 1, strip = r >> 1;   // strip in [0,25)
    const int t = threadIdx.x;
    const int w = t >> 6, l = t & 63;
    const int lane31 = l & 31, lhalf = l >> 5;
    const int s = hi * 3200 + strip * 128 + w * 32 + lane31;

    const _Float16* pB = in + (size_t)(n * HW + s) * 128 + lhalf * 8;
    const _Float16* pA0 = wblob + (size_t)(coH * 2) * 8 * 512 + l * 8;
    const _Float16* pA1 = pA0 + 8 * 512;

    half8 bB[8], bA0[8], bA1[8];
#pragma unroll
    for (int c = 0; c < 8; ++c) {
        bB[c]  = *(const half8*)(pB + c * 16);
        bA0[c] = *(const half8*)(pA0 + (size_t)c * 512);
        bA1[c] = *(const half8*)(pA1 + (size_t)c * 512);
    }
    f32x16 acc0 = {}, acc1 = {};
#pragma unroll
    for (int c = 0; c < 8; ++c) {
        acc0 = __builtin_amdgcn_mfma_f32_32x32x16_f16(bA0[c], bB[c], acc0, 0, 0, 0);
        acc1 = __builtin_amdgcn_mfma_f32_32x32x16_f16(bA1[c], bB[c], acc1, 0, 0, 0);
    }

#pragma unroll
    for (int ct = 0; ct < 2; ++ct) {
        const f32x16& acc = ct ? acc1 : acc0;
#pragma unroll
        for (int q = 0; q < 4; ++q) {
            const int co0 = coH * 64 + ct * 32 + 8 * q + 4 * lhalf;
            if (MODE == 0) {
                const int hd = co0 >> 4, dd = co0 & 15;
                float4 fv = {acc[4 * q + 0] + bias[co0 + 0], acc[4 * q + 1] + bias[co0 + 1],
                             acc[4 * q + 2] + bias[co0 + 2], acc[4 * q + 3] + bias[co0 + 3]};
                *(float4*)&outp[((size_t)(n * 8 + hd) * HW + s) * 16 + dd] = fv;
            } else {
#pragma unroll
                for (int i = 0; i < 4; ++i)
                    outp[(size_t)(n * 128 + co0 + i) * HW + s] = acc[4 * q + i] + bias[co0 + i];
            }
        }
    }
}

// ---------------------------------------------------------------------------
// Deformable attention v3 (PROVEN round 10: part of 219.2us): point-pair
// split, all gathers parallel. 8 threads/site = 4 d-groups x 2 point-halves;
// each thread issues its 16 gathers upfront, partial softmax over its 4
// points, then exact pairwise merge with partner t^4 via shfl_xor. ~110 live
// regs -> (256,4) caps 128 = 4 waves/SIMD; 16 outstanding loads/thread.
// grid (32 slices, 200 tiles), block 256 = 32 sites x 8 subthreads.
// v_s [nb][s][16] fp32; offs NHWC fp32; att fp16 rows [n][s][128].
// ---------------------------------------------------------------------------
__global__ __launch_bounds__(256, 4) void deform_attn_kernel(
    const float* __restrict__ v_s, const float* __restrict__ offs,
    const float* __restrict__ ref, _Float16* __restrict__ att) {
    const int slice = blockIdx.x;
    const int n = slice >> 3, hd = slice & 7;
    const int t = threadIdx.x;
    const int s = blockIdx.y * 32 + (t >> 3);
    const int sub = t & 7;
    const int d0 = (sub & 3) * 4;
    const int ph = sub >> 2;                 // point half: points ph*4..ph*4+3
    const int nb = n * 8 + hd;
    const float* vbase = v_s + (size_t)nb * (HW * 16) + d0;

    const float4 cv = *(const float4*)&v_s[((size_t)nb * HW + s) * 16 + d0];
    const float rx = ref[(size_t)(n * HW + s) * 2 + 0] * 80.f - 0.5f;
    const float ry = ref[(size_t)(n * HW + s) * 2 + 1] * 80.f - 0.5f;

    const int e = (s >= 3200) ? 1 : 0;
    const float* ob0 = offs + ((size_t)n * HW + (2 * s - e * HW)) * 128 + hd * 16 + e;

    // ---- own half's offset loads (point q=ph*4+j: x at ob0[8ph+2j], y +128)
    float4 oxv0 = *(const float4*)(ob0 + 8 * ph);
    float4 oxv1 = *(const float4*)(ob0 + 8 * ph + 4);
    float4 oyv0 = *(const float4*)(ob0 + 128 + 8 * ph);
    float4 oyv1 = *(const float4*)(ob0 + 128 + 8 * ph + 4);
    float ox[4] = {oxv0.x, oxv0.z, oxv1.x, oxv1.z};
    float oy[4] = {oyv0.x, oyv0.z, oyv1.x, oyv1.z};

    // ---- coordinates/weights for own 4 points ----
    float wx1[4], wy1[4];
    int ix[4], iy[4];
#pragma unroll
    for (int p = 0; p < 4; ++p) {
        const float px = rx + ox[p];
        const float py = ry + oy[p];
        const float fx = floorf(px), fy = floorf(py);
        ix[p] = (int)fx; iy[p] = (int)fy;
        wx1[p] = px - fx; wy1[p] = py - fy;
    }

    // ---- all 16 gathers issued upfront (clamped, unconditional) ----
    float4 g[4][4];
#pragma unroll
    for (int p = 0; p < 4; ++p) {
        const int xc0 = min(max(ix[p], 0), 79),     xc1 = min(max(ix[p] + 1, 0), 79);
        const int yc0 = min(max(iy[p], 0), 79),     yc1 = min(max(iy[p] + 1, 0), 79);
        const int r0 = yc0 * 80, r1 = yc1 * 80;
        g[p][0] = *(const float4*)(vbase + (size_t)(r0 + xc0) * 16);
        g[p][1] = *(const float4*)(vbase + (size_t)(r0 + xc1) * 16);
        g[p][2] = *(const float4*)(vbase + (size_t)(r1 + xc0) * 16);
        g[p][3] = *(const float4*)(vbase + (size_t)(r1 + xc1) * 16);
    }

    // ---- combine, score (reduce over d-groups: lanes t^1, t^2) ----
    float4 sampled[4];
    float score[4];
#pragma unroll
    for (int p = 0; p < 4; ++p) {
        const float vx0 = (ix[p] >= 0 && ix[p] < Ww) ? 1.f : 0.f;
        const float vx1 = (ix[p] + 1 >= 0 && ix[p] + 1 < Ww) ? 1.f : 0.f;
        const float vy0 = (iy[p] >= 0 && iy[p] < Hh) ? 1.f : 0.f;
        const float vy1 = (iy[p] + 1 >= 0 && iy[p] + 1 < Hh) ? 1.f : 0.f;
        const float wx0 = 1.f - wx1[p], wy0 = 1.f - wy1[p];
        const float w00 = wx0 * wy0 * vx0 * vy0;
        const float w01 = wx1[p] * wy0 * vx1 * vy0;
        const float w10 = wx0 * wy1[p] * vx0 * vy1;
        const float w11 = wx1[p] * wy1[p] * vx1 * vy1;
        float4 sv;
        sv.x = g[p][0].x * w00 + g[p][1].x * w01 + g[p][2].x * w10 + g[p][3].x * w11;
        sv.y = g[p][0].y * w00 + g[p][1].y * w01 + g[p][2].y * w10 + g[p][3].y * w11;
        sv.z = g[p][0].z * w00 + g[p][1].z * w01 + g[p][2].z * w10 + g[p][3].z * w11;
        sv.w = g[p][0].w * w00 + g[p][1].w * w01 + g[p][2].w * w10 + g[p][3].w * w11;
        sampled[p] = sv;
        float sc = sv.x * cv.x + sv.y * cv.y + sv.z * cv.z + sv.w * cv.w;
        sc += __shfl_xor(sc, 1);
        sc += __shfl_xor(sc, 2);
        score[p] = sc;
    }

    // ---- partial softmax over own 4 points ----
    float m = score[0];
#pragma unroll
    for (int p = 1; p < 4; ++p) m = fmaxf(m, score[p]);
    float sum = 0.f;
    float4 o = {0.f, 0.f, 0.f, 0.f};
#pragma unroll
    for (int p = 0; p < 4; ++p) {
        const float aw = __expf(score[p] - m);
        sum += aw;
        o.x += aw * sampled[p].x;
        o.y += aw * sampled[p].y;
        o.z += aw * sampled[p].z;
        o.w += aw * sampled[p].w;
    }

    // ---- merge with partner half (lane t^4): exact online-softmax merge ----
    const float m2   = __shfl_xor(m, 4);
    const float sum2 = __shfl_xor(sum, 4);
    float4 o2;
    o2.x = __shfl_xor(o.x, 4);
    o2.y = __shfl_xor(o.y, 4);
    o2.z = __shfl_xor(o.z, 4);
    o2.w = __shfl_xor(o.w, 4);
    const float mn = fmaxf(m, m2);
    const float sA = __expf(m - mn), sB = __expf(m2 - mn);
    const float tot = sum * sA + sum2 * sB;
    const float inv = 1.f / tot;
    o.x = (o.x * sA + o2.x * sB) * inv;
    o.y = (o.y * sA + o2.y * sB) * inv;
    o.z = (o.z * sA + o2.z * sB) * inv;
    o.w = (o.w * sA + o2.w * sB) * inv;

    if (ph == 0) {
        half4v hv = {(_Float16)o.x, (_Float16)o.y, (_Float16)o.z, (_Float16)o.w};
        *(half4v*)&att[((size_t)n * HW + s) * 128 + hd * 16 + d0] = hv;
    }
}

// ---------------------------------------------------------------------------
extern "C" void kernel_launch(void* const* d_in, const int* in_sizes, int n_in,
                              void* d_out, int out_size, void* d_ws, size_t ws_size,
                              hipStream_t stream) {
    const float* query = (const float*)d_in[0];
    const float* value = (const float*)d_in[1];
    const float* ref   = (const float*)d_in[2];
    const float* co_w1 = (const float*)d_in[3];
    const float* co_b1 = (const float*)d_in[4];
    const float* co_w2 = (const float*)d_in[5];
    const float* co_b2 = (const float*)d_in[6];
    const float* co_w3 = (const float*)d_in[7];
    const float* co_b3 = (const float*)d_in[8];
    const float* co_w4 = (const float*)d_in[9];
    const float* co_b4 = (const float*)d_in[10];
    const float* val_w = (const float*)d_in[11];
    const float* val_b = (const float*)d_in[12];
    const float* out_w = (const float*)d_in[13];
    const float* out_b = (const float*)d_in[14];

    char* ws = (char*)d_ws;
    size_t o = 0;
    auto alloc = [&](size_t bytes) { char* p = ws + o; o += (bytes + 255) & ~(size_t)255; return p; };

    _Float16* wb2 = (_Float16*)alloc(147456 * 2);
    _Float16* wb3 = (_Float16*)alloc(147456 * 2);
    _Float16* wb4 = (_Float16*)alloc(147456 * 2);
    _Float16* wbv = (_Float16*)alloc(16384 * 2);
    _Float16* wbo = (_Float16*)alloc(16384 * 2);
    char* vsR = alloc(3276800 * 4);            // v_s fp32 [32][6400][16]
    float* v_s = (float*)vsR;
    _Float16* wb1 = (_Float16*)vsR;            // alias: wb1 dead before v_s written
    _Float16* v_h = (_Float16*)alloc((size_t)NB * HW * 128 * 2);  // 6.55 MB
    char* R1 = alloc((size_t)NB * 8 * PS * 32 * 2);  // 13.77 MB
    _Float16* q_h = (_Float16*)R1;             // fp16 planar [4][8][PS][32]
    float* o4 = (float*)R1;                    // fp32 NHWC [4][6400][128]; q_h dead
    char* R2 = alloc((size_t)NB * 4 * PS * 32 * 2 * 2);  // 13.78 MB
    _Float16* hA = (_Float16*)R2;              // fp16 planar [4][4][PS][32]
    _Float16* hB = (_Float16*)(R2 + (size_t)NB * 4 * PS * 32 * 2);
    _Float16* att_h = (_Float16*)R2;           // fp16 [4][6400][128]; hA dead by then

    // fused prep + transposes (independent work, block-range dispatch)
    prep_all<<<5104, 256, 0, stream>>>(co_w1, co_w2, co_w3, co_w4, val_w, out_w,
                                       wb1, wb2, wb3, wb4, wbv, wbo,
                                       (int*)q_h, (int*)hA, (int*)hB,
                                       query, value, q_h, v_h);

    // conv1 (must precede val-conv: wb1 aliases v_s region)
    conv3x3_mfma<8, 1><<<400, 256, 0, stream>>>(q_h, wb1, co_b1, hA);

    // v = 1x1 conv(value) -> v_s (NHWC-16 fp32)
    conv1x1_mfma<0><<<400, 256, 0, stream>>>(v_h, wbv, val_b, v_s);

    // rest of offset conv stack
    conv3x3_mfma<4, 1><<<400, 256, 0, stream>>>(hA, wb2, co_b2, hB);
    conv3x3_mfma<4, 1><<<400, 256, 0, stream>>>(hB, wb3, co_b3, hA);
    conv3x3_mfma<4, 2><<<400, 256, 0, stream>>>(hA, wb4, co_b4, o4);

    // deformable attention -> att_h (fp16 rows), XCD-pinned slices
    deform_attn_kernel<<<dim3(32, 200), 256, 0, stream>>>(v_s, o4, ref, att_h);

    // final 1x1 conv -> d_out (NCHW fp32)
    conv1x1_mfma<1><<<400, 256, 0, stream>>>(att_h, wbo, out_b, (float*)d_out);
}

// Round 12
// 217.626 us; speedup vs baseline: 1.0692x; 1.0692x over previous
//
#include <hip/hip_runtime.h>
#include <math.h>

#define Hh 80
#define Ww 80
#define HW 6400
#define PS 6724      // 82*82 padded spatial
#define NB 4

typedef _Float16 half8 __attribute__((ext_vector_type(8)));
typedef _Float16 half4v __attribute__((ext_vector_type(4)));
typedef float f32x16 __attribute__((ext_vector_type(16)));

// async global->LDS, 16B per lane. Dest is wave-uniform base (+lane*16 by HW);
// src is per-lane.
__device__ __forceinline__ void gload16(const _Float16* g, _Float16* l) {
    __builtin_amdgcn_global_load_lds(
        (const __attribute__((address_space(1))) void*)g,
        (__attribute__((address_space(3))) void*)l, 16, 0, 0);
}

// counted vmcnt wait (literal N) + full memory fence against code motion
#define WAITVM(N) asm volatile("s_waitcnt vmcnt(" #N ")" ::: "memory")
// issue-point pin: loads/stores cannot cross a memory clobber
#define FENCE() asm volatile("" ::: "memory")

__device__ __forceinline__ void barrier_mem() {
    asm volatile("" ::: "memory");
    __builtin_amdgcn_s_barrier();
    asm volatile("" ::: "memory");
}

// ---------------------------------------------------------------------------
// wblob helpers (weight-blob packing for MFMA A-operands)
// conv3x3 blob: flat = (CT*NS + c*18 + tap*2 + h)*512 + lane*8 + j
//   co = CT*32 + (lane&31);  ci = c*32 + h*16 + (lane>>5)*8 + j
// conv1x1 blob: flat = ((CT*8 + c)*64 + lane)*8 + j
//   co = CT*32 + (lane&31);  ci = c*16 + (lane>>5)*8 + j
// ---------------------------------------------------------------------------
__device__ inline void wblob_one(const float* src, _Float16* dst, int CI, int d) {
    int NC = CI / 32;
    int j = d & 7;
    int l = (d >> 3) & 63;
    int h = (d >> 9) & 1;
    int rest = d >> 10;
    int tap = rest % 9;
    rest /= 9;
    int c = rest % NC;
    int CT = rest / NC;
    int co = CT * 32 + (l & 31);
    int ci = c * 32 + h * 16 + (l >> 5) * 8 + j;
    dst[d] = (_Float16)src[((size_t)co * CI + ci) * 9 + tap];
}

__device__ inline void wblob1x1_one(const float* src, _Float16* dst, int d) {
    int j = d & 7;
    int l = (d >> 3) & 63;
    int c = (d >> 9) & 7;
    int CT = d >> 12;
    int co = CT * 32 + (l & 31);
    int ci = c * 16 + (l >> 5) * 8 + j;
    dst[d] = (_Float16)src[co * 128 + ci];
}

__device__ inline int padsite(int p) {
    if (p < 82) return p;                       // row 0
    if (p < 164) return 81 * 82 + (p - 82);     // row 81
    if (p < 244) return (p - 163) * 82;         // col 0, rows 1..80
    return (p - 243) * 82 + 81;                 // col 81, rows 1..80
}

// ---------------------------------------------------------------------------
// prep_all: fused {wblob prep + pad zeroing} U {q_transpose} U {v_transpose}.
// All three are mutually independent -> block-range dispatch, no interaction.
// b in [0,4304): prep; [4304,4704): q_transpose; [4704,5104): v_transpose.
// Both transpose offsets are multiples of 8 -> XCD pinning (b&7) preserved.
// (round-7 win: 3 launches -> 1, -4.6us)
// ---------------------------------------------------------------------------
__global__ __launch_bounds__(256) void prep_all(
    const float* __restrict__ w1, const float* __restrict__ w2,
    const float* __restrict__ w3, const float* __restrict__ w4,
    const float* __restrict__ vw, const float* __restrict__ ow,
    _Float16* __restrict__ b1, _Float16* __restrict__ b2,
    _Float16* __restrict__ b3, _Float16* __restrict__ b4,
    _Float16* __restrict__ bv, _Float16* __restrict__ bo,
    int* __restrict__ qh_i, int* __restrict__ hA_i, int* __restrict__ hB_i,
    const float* __restrict__ query, const float* __restrict__ value,
    _Float16* __restrict__ q_h, _Float16* __restrict__ v_h) {
    __shared__ _Float16 T[64 * 264];            // max(256+8, 128+8) stride tile
    const int blk = blockIdx.x;
    const int t = threadIdx.x;

    if (blk < 4304) {                           // ---- prep ----
        int idx = blk * 256 + t;
        if (idx < 294912) { wblob_one(w1, b1, 256, idx); return; }
        idx -= 294912;
        if (idx < 147456) { wblob_one(w2, b2, 128, idx); return; }
        idx -= 147456;
        if (idx < 147456) { wblob_one(w3, b3, 128, idx); return; }
        idx -= 147456;
        if (idx < 147456) { wblob_one(w4, b4, 128, idx); return; }
        idx -= 147456;
        if (idx < 16384) { wblob1x1_one(vw, bv, idx); return; }
        idx -= 16384;
        if (idx < 16384) { wblob1x1_one(ow, bo, idx); return; }
        idx -= 16384;
        if (idx < 165888) {  // q_h pads: 4n x 8c x 324 sites x 16 ints
            int n = idx / 41472, rr = idx % 41472;
            int c = rr / 5184, r2 = rr % 5184;
            int p = r2 >> 4, k = r2 & 15;
            qh_i[((size_t)(n * 8 + c) * PS + padsite(p)) * 16 + k] = 0;
            return;
        }
        idx -= 165888;
        if (idx < 82944) {   // hA pads
            int n = idx / 20736, rr = idx % 20736;
            int c = rr / 5184, r2 = rr % 5184;
            int p = r2 >> 4, k = r2 & 15;
            hA_i[((size_t)(n * 4 + c) * PS + padsite(p)) * 16 + k] = 0;
            return;
        }
        idx -= 82944;
        if (idx < 82944) {   // hB pads
            int n = idx / 20736, rr = idx % 20736;
            int c = rr / 5184, r2 = rr % 5184;
            int p = r2 >> 4, k = r2 & 15;
            hB_i[((size_t)(n * 4 + c) * PS + padsite(p)) * 16 + k] = 0;
        }
        return;
    }

    if (blk < 4704) {                           // ---- q_transpose ----
        const int b = blk - 4304;
        const int xcd = b & 7, n = xcd & 3, hi = xcd >> 2;
        const int s0 = hi * 3200 + (b >> 3) * 64;
        constexpr int CI = 256, ST = CI + 8;
        for (int idx = t; idx < 64 * CI; idx += 256) {
            int ci = idx >> 6, sl = idx & 63;
            T[sl * ST + ci] = (_Float16)query[((size_t)n * CI + ci) * HW + s0 + sl];
        }
        __syncthreads();
        for (int idx = t; idx < 64 * 32; idx += 256) {
            int q = idx & 31, sl = idx >> 5;
            int s = s0 + sl, yy = s / 80, xx = s % 80;
            int c = q >> 2, off = (q & 3) * 8;
            *(int4*)(q_h + ((size_t)(n * 8 + c) * PS + (yy + 1) * 82 + (xx + 1)) * 32 + off) =
                *(const int4*)(&T[sl * ST + q * 8]);
        }
        return;
    }

    {                                           // ---- v_transpose ----
        const int b = blk - 4704;
        const int xcd = b & 7, n = xcd & 3, hi = xcd >> 2;
        const int s0 = hi * 3200 + (b >> 3) * 64;
        constexpr int CI = 128, ST = CI + 8;
        for (int idx = t; idx < 64 * CI; idx += 256) {
            int ci = idx >> 6, sl = idx & 63;
            T[sl * ST + ci] = (_Float16)value[((size_t)n * CI + ci) * HW + s0 + sl];
        }
        __syncthreads();
        for (int idx = t; idx < 64 * 16; idx += 256) {
            int q = idx & 15, sl = idx >> 4;
            *(int4*)(v_h + ((size_t)n * HW + s0 + sl) * CI + q * 8) =
                *(const int4*)(&T[sl * ST + q * 8]);
        }
    }
}

// ---------------------------------------------------------------------------
// MFMA implicit-GEMM 3x3 conv body, v8 (PROVEN rounds 8/10: part of 219.2us).
// v6 geometry (4 waves x 1co x 2sp over 16x4 region, XCD-pinned, B dbuf in
// LDS via global_load_lds) with A (weights) in a PER-GROUP VGPR double-buffer
// (aA/aB, 6 x half8 = 24 VGPR each). Each group: {issue 6 A-loads; FENCE;
// compute 12 MFMA}. LDS 24 KB (B only), barriers 2/chunk at B-buffer flips
// with WAITVM(12). v9's (2co x 1sp) regressed (+13.5us: doubled A traffic);
// v5/v9 bracket this as the local optimum for the 400-block geometry.
// Refactored as a __device__ body(b, ...) so conv1 can be block-range fused
// with the independent val-conv (round 12).
// ACT 1: leaky -> chunked-planar fp16 [n][4c][PS][32].
// ACT 2: 10*tanh -> fp32 NHWC [n][6400][128].
// ---------------------------------------------------------------------------
template <int NCp, int ACT>
__device__ __forceinline__ void conv3x3_body(
    int b, const _Float16* __restrict__ in, const _Float16* __restrict__ wblob,
    const float* __restrict__ bias, void* __restrict__ outp) {
    constexpr int NS = NCp * 18;
    static_assert((NCp & 1) == 0, "pair loop needs even NCp");
    __shared__ _Float16 Bbuf[2][6 * 1024];   // 2 x 12KB (B only)

    const int xcd = b & 7, n = xcd & 3, hi = xcd >> 2;
    const int r = b >> 3;                    // 0..49: 16x4 region
    const int x0 = (r % 5) * 16, y0 = hi * 40 + (r / 5) * 4;
    const int t = threadIdx.x;
    const int w = t >> 6, l = t & 63;        // w = co-tile
    const int lane31 = l & 31, lhalf = l >> 5;
    const int lx = lane31 & 15, lyw = lane31 >> 4;
    const int si = l & 15, g8 = l >> 4;      // staging: site / granule of lane

    const _Float16* bplane0 = in + (size_t)(n * NCp) * PS * 32;
    const _Float16* wA = wblob + (size_t)w * NS * 512 + l * 8;   // per-lane A src

    f32x16 acc0 = {}, acc1 = {};
    half8 aA[6], aB[6];                      // per-group A register dbuf

    // stage B-tile (6 rows x 2 segs) of a chunk plane into Bbuf[par] (3 loads/wave)
    auto stageB = [&](const _Float16* plane, int par) {
#pragma unroll
        for (int j = 0; j < 3; ++j) {
            const int m = 3 * w + j, rr = m >> 1, sg = m & 1;
            gload16(plane + ((size_t)((y0 + rr) * 82 + x0 + sg * 16 + si)) * 32 + g8 * 8,
                    &Bbuf[par][rr * 1024 + sg * 512]);
        }
    };
    // load the 6 A-frags of 6-substep group grp into a register buffer
    auto loadA6 = [&](half8 (&ar)[6], int grp) {
        const _Float16* asrc = wA + (size_t)grp * 6 * 512;
#pragma unroll
        for (int k2 = 0; k2 < 6; ++k2)
            ar[k2] = *(const half8*)(asrc + (size_t)k2 * 512);
    };
    // compute the 6 substeps of sub-group gi from reg-A + LDS-B (12 MFMA)
    auto compute6 = [&](int gi, const half8 (&ar)[6], const _Float16* bb) {
#pragma unroll
        for (int k = 0; k < 6; ++k) {
            const int u = gi * 6 + k;            // compile-time after inline
            const int tap = u >> 1, h = u & 1;
            const int dy = tap / 3, dx = tap % 3;
            const int cx = lx + dx;
            const int boff = (cx >> 4) * 512 + (h * 2 + lhalf) * 128 + (cx & 15) * 8;
            half8 b0 = *(const half8*)&bb[(lyw + dy) * 1024 + boff];
            half8 b1 = *(const half8*)&bb[(lyw + 2 + dy) * 1024 + boff];
            acc0 = __builtin_amdgcn_mfma_f32_32x32x16_f16(ar[k], b0, acc0, 0, 0, 0);
            acc1 = __builtin_amdgcn_mfma_f32_32x32x16_f16(ar[k], b1, acc1, 0, 0, 0);
        }
    };

    // ---- prologue: B(chunk0) + A(group0), drained once ----
    stageB(bplane0, 0);
    loadA6(aA, 0);
    WAITVM(0);
    barrier_mem();

#pragma unroll 1
    for (int cp = 0; cp < NCp / 2; ++cp) {
        const int c0 = 2 * cp;
        const bool lastp = (cp == NCp / 2 - 1);
        const _Float16* plane1 = bplane0 + (size_t)(c0 + 1) * PS * 32;
        const _Float16* plane2 = bplane0 + (size_t)(c0 + 2) * PS * 32;
        // g0: issue A(c0,g1)+B(c1), pin, compute (c0,g0) from Bbuf0
        loadA6(aB, c0 * 3 + 1);
        stageB(plane1, 1);
        FENCE();
        compute6(0, aA, Bbuf[0]);
        // g1
        loadA6(aA, c0 * 3 + 2);
        FENCE();
        compute6(1, aB, Bbuf[0]);
        // g2: flip to Bbuf1 after this group
        loadA6(aB, c0 * 3 + 3);
        FENCE();
        compute6(2, aA, Bbuf[0]);
        WAITVM(12);          // B(c1) retired (12 loads issued after it)
        barrier_mem();       // all waves done reading Bbuf0; Bbuf1 visible
        // g3: stage next pair's even-chunk B into Bbuf0 (safe: post-barrier)
        loadA6(aA, c0 * 3 + 4);
        if (!lastp) stageB(plane2, 0);
        FENCE();
        compute6(0, aB, Bbuf[1]);
        // g4
        loadA6(aB, c0 * 3 + 5);
        FENCE();
        compute6(1, aA, Bbuf[1]);
        // g5: flip back to Bbuf0 (unless done)
        if (!lastp) {
            loadA6(aA, c0 * 3 + 6);
            FENCE();
            compute6(2, aB, Bbuf[1]);
            WAITVM(12);      // B(c0+2) retired (12 loads issued after it)
            barrier_mem();
        } else {
            FENCE();
            compute6(2, aB, Bbuf[1]);
        }
    }

    // epilogue: D col(site)=lane&31 -> (y=y0+lyw+2f, x=x0+lx);
    // row(co)=(reg&3)+8*(reg>>2)+4*(lane>>5)
    const int x = x0 + lx;
#pragma unroll
    for (int f = 0; f < 2; ++f) {
        const f32x16& acc = f ? acc1 : acc0;
        const int y = y0 + lyw + 2 * f;
#pragma unroll
        for (int q = 0; q < 4; ++q) {
            const int inner = 8 * q + 4 * lhalf;
            const int co0 = w * 32 + inner;
            float v[4];
#pragma unroll
            for (int i = 0; i < 4; ++i) {
                float vv = acc[q * 4 + i] + bias[co0 + i];
                if (ACT == 1) vv = (vv >= 0.f) ? vv : 0.1f * vv;
                else vv = 10.f * tanhf(vv);
                v[i] = vv;
            }
            if (ACT == 1) {
                half4v hv = {(_Float16)v[0], (_Float16)v[1], (_Float16)v[2], (_Float16)v[3]};
                *(half4v*)((_Float16*)outp +
                    ((size_t)(n * 4 + w) * PS + (y + 1) * 82 + (x + 1)) * 32 + inner) = hv;
            } else {
                float4 fv = {v[0], v[1], v[2], v[3]};
                *(float4*)((float*)outp + ((size_t)n * HW + y * 80 + x) * 128 + co0) = fv;
            }
        }
    }
}

template <int NCp, int ACT>
__global__ __launch_bounds__(256, 2) void conv3x3_mfma(
    const _Float16* __restrict__ in, const _Float16* __restrict__ wblob,
    const float* __restrict__ bias, void* __restrict__ outp) {
    conv3x3_body<NCp, ACT>(blockIdx.x, in, wblob, bias, outp);
}

// ---------------------------------------------------------------------------
// MFMA 1x1 conv body (K=128), fp16 rows [n][s][128] in, fp32 out.
// Barrier-free, XCD-pinned. Block 256 = 4 waves x 32 sites; wave = 64co.
// All 24 loads issued before the 16 MFMAs.
// MODE 0: out v_s fp32 [n*8+hd][s][16].  MODE 1: out fp32 NCHW.
// ---------------------------------------------------------------------------
template <int MODE>
__device__ __forceinline__ void conv1x1_body(
    int b, const _Float16* __restrict__ in, const _Float16* __restrict__ wblob,
    const float* __restrict__ bias, float* __restrict__ outp) {
    const int xcd = b & 7, n = xcd & 3, hi = xcd >> 2;
    const int r = b >> 3;                    // 0..49
    const int coH = r & 1, strip = r >> 1;   // strip in [0,25)
    const int t = threadIdx.x;
    const int w = t >> 6, l = t & 63;
    const int lane31 = l & 31, lhalf = l >> 5;
    const int s = hi * 3200 + strip * 128 + w * 32 + lane31;

    const _Float16* pB = in + (size_t)(n * HW + s) * 128 + lhalf * 8;
    const _Float16* pA0 = wblob + (size_t)(coH * 2) * 8 * 512 + l * 8;
    const _Float16* pA1 = pA0 + 8 * 512;

    half8 bB[8], bA0[8], bA1[8];
#pragma unroll
    for (int c = 0; c < 8; ++c) {
        bB[c]  = *(const half8*)(pB + c * 16);
        bA0[c] = *(const half8*)(pA0 + (size_t)c * 512);
        bA1[c] = *(const half8*)(pA1 + (size_t)c * 512);
    }
    f32x16 acc0 = {}, acc1 = {};
#pragma unroll
    for (int c = 0; c < 8; ++c) {
        acc0 = __builtin_amdgcn_mfma_f32_32x32x16_f16(bA0[c], bB[c], acc0, 0, 0, 0);
        acc1 = __builtin_amdgcn_mfma_f32_32x32x16_f16(bA1[c], bB[c], acc1, 0, 0, 0);
    }

#pragma unroll
    for (int ct = 0; ct < 2; ++ct) {
        const f32x16& acc = ct ? acc1 : acc0;
#pragma unroll
        for (int q = 0; q < 4; ++q) {
            const int co0 = coH * 64 + ct * 32 + 8 * q + 4 * lhalf;
            if (MODE == 0) {
                const int hd = co0 >> 4, dd = co0 & 15;
                float4 fv = {acc[4 * q + 0] + bias[co0 + 0], acc[4 * q + 1] + bias[co0 + 1],
                             acc[4 * q + 2] + bias[co0 + 2], acc[4 * q + 3] + bias[co0 + 3]};
                *(float4*)&outp[((size_t)(n * 8 + hd) * HW + s) * 16 + dd] = fv;
            } else {
#pragma unroll
                for (int i = 0; i < 4; ++i)
                    outp[(size_t)(n * 128 + co0 + i) * HW + s] = acc[4 * q + i] + bias[co0 + i];
            }
        }
    }
}

template <int MODE>
__global__ __launch_bounds__(256) void conv1x1_mfma(
    const _Float16* __restrict__ in, const _Float16* __restrict__ wblob,
    const float* __restrict__ bias, float* __restrict__ outp) {
    conv1x1_body<MODE>(blockIdx.x, in, wblob, bias, outp);
}

// ---------------------------------------------------------------------------
// Fused conv1 (3x3, NCp=8, leaky) U val-conv (1x1, MODE 0): data-independent
// once wb1 is de-aliased from v_s (round-12). Block-range dispatch:
// b in [0,400) -> conv1; [400,800) -> val-conv (400 % 8 == 0 preserves XCD
// pinning). Fills conv1's 1.56-blocks/CU wave-quantization tail with
// val-conv work; saves one launch (~2.3us).
// ---------------------------------------------------------------------------
__global__ __launch_bounds__(256, 2) void conv1_val_fused(
    const _Float16* __restrict__ q_h, const _Float16* __restrict__ wb1,
    const float* __restrict__ co_b1, void* __restrict__ hA,
    const _Float16* __restrict__ v_h, const _Float16* __restrict__ wbv,
    const float* __restrict__ val_b, float* __restrict__ v_s) {
    const int b = blockIdx.x;
    if (b < 400) {
        conv3x3_body<8, 1>(b, q_h, wb1, co_b1, hA);
    } else {
        conv1x1_body<0>(b - 400, v_h, wbv, val_b, v_s);
    }
}

// ---------------------------------------------------------------------------
// Deformable attention v3 (PROVEN round 10: part of 219.2us): point-pair
// split, all gathers parallel. 8 threads/site = 4 d-groups x 2 point-halves;
// each thread issues its 16 gathers upfront, partial softmax over its 4
// points, then exact pairwise merge with partner t^4 via shfl_xor. ~110 live
// regs -> (256,4) caps 128 = 4 waves/SIMD; 16 outstanding loads/thread.
// grid (32 slices, 200 tiles), block 256 = 32 sites x 8 subthreads.
// v_s [nb][s][16] fp32; offs NHWC fp32; att fp16 rows [n][s][128].
// ---------------------------------------------------------------------------
__global__ __launch_bounds__(256, 4) void deform_attn_kernel(
    const float* __restrict__ v_s, const float* __restrict__ offs,
    const float* __restrict__ ref, _Float16* __restrict__ att) {
    const int slice = blockIdx.x;
    const int n = slice >> 3, hd = slice & 7;
    const int t = threadIdx.x;
    const int s = blockIdx.y * 32 + (t >> 3);
    const int sub = t & 7;
    const int d0 = (sub & 3) * 4;
    const int ph = sub >> 2;                 // point half: points ph*4..ph*4+3
    const int nb = n * 8 + hd;
    const float* vbase = v_s + (size_t)nb * (HW * 16) + d0;

    const float4 cv = *(const float4*)&v_s[((size_t)nb * HW + s) * 16 + d0];
    const float rx = ref[(size_t)(n * HW + s) * 2 + 0] * 80.f - 0.5f;
    const float ry = ref[(size_t)(n * HW + s) * 2 + 1] * 80.f - 0.5f;

    const int e = (s >= 3200) ? 1 : 0;
    const float* ob0 = offs + ((size_t)n * HW + (2 * s - e * HW)) * 128 + hd * 16 + e;

    // ---- own half's offset loads (point q=ph*4+j: x at ob0[8ph+2j], y +128)
    float4 oxv0 = *(const float4*)(ob0 + 8 * ph);
    float4 oxv1 = *(const float4*)(ob0 + 8 * ph + 4);
    float4 oyv0 = *(const float4*)(ob0 + 128 + 8 * ph);
    float4 oyv1 = *(const float4*)(ob0 + 128 + 8 * ph + 4);
    float ox[4] = {oxv0.x, oxv0.z, oxv1.x, oxv1.z};
    float oy[4] = {oyv0.x, oyv0.z, oyv1.x, oyv1.z};

    // ---- coordinates/weights for own 4 points ----
    float wx1[4], wy1[4];
    int ix[4], iy[4];
#pragma unroll
    for (int p = 0; p < 4; ++p) {
        const float px = rx + ox[p];
        const float py = ry + oy[p];
        const float fx = floorf(px), fy = floorf(py);
        ix[p] = (int)fx; iy[p] = (int)fy;
        wx1[p] = px - fx; wy1[p] = py - fy;
    }

    // ---- all 16 gathers issued upfront (clamped, unconditional) ----
    float4 g[4][4];
#pragma unroll
    for (int p = 0; p < 4; ++p) {
        const int xc0 = min(max(ix[p], 0), 79),     xc1 = min(max(ix[p] + 1, 0), 79);
        const int yc0 = min(max(iy[p], 0), 79),     yc1 = min(max(iy[p] + 1, 0), 79);
        const int r0 = yc0 * 80, r1 = yc1 * 80;
        g[p][0] = *(const float4*)(vbase + (size_t)(r0 + xc0) * 16);
        g[p][1] = *(const float4*)(vbase + (size_t)(r0 + xc1) * 16);
        g[p][2] = *(const float4*)(vbase + (size_t)(r1 + xc0) * 16);
        g[p][3] = *(const float4*)(vbase + (size_t)(r1 + xc1) * 16);
    }

    // ---- combine, score (reduce over d-groups: lanes t^1, t^2) ----
    float4 sampled[4];
    float score[4];
#pragma unroll
    for (int p = 0; p < 4; ++p) {
        const float vx0 = (ix[p] >= 0 && ix[p] < Ww) ? 1.f : 0.f;
        const float vx1 = (ix[p] + 1 >= 0 && ix[p] + 1 < Ww) ? 1.f : 0.f;
        const float vy0 = (iy[p] >= 0 && iy[p] < Hh) ? 1.f : 0.f;
        const float vy1 = (iy[p] + 1 >= 0 && iy[p] + 1 < Hh) ? 1.f : 0.f;
        const float wx0 = 1.f - wx1[p], wy0 = 1.f - wy1[p];
        const float w00 = wx0 * wy0 * vx0 * vy0;
        const float w01 = wx1[p] * wy0 * vx1 * vy0;
        const float w10 = wx0 * wy1[p] * vx0 * vy1;
        const float w11 = wx1[p] * wy1[p] * vx1 * vy1;
        float4 sv;
        sv.x = g[p][0].x * w00 + g[p][1].x * w01 + g[p][2].x * w10 + g[p][3].x * w11;
        sv.y = g[p][0].y * w00 + g[p][1].y * w01 + g[p][2].y * w10 + g[p][3].y * w11;
        sv.z = g[p][0].z * w00 + g[p][1].z * w01 + g[p][2].z * w10 + g[p][3].z * w11;
        sv.w = g[p][0].w * w00 + g[p][1].w * w01 + g[p][2].w * w10 + g[p][3].w * w11;
        sampled[p] = sv;
        float sc = sv.x * cv.x + sv.y * cv.y + sv.z * cv.z + sv.w * cv.w;
        sc += __shfl_xor(sc, 1);
        sc += __shfl_xor(sc, 2);
        score[p] = sc;
    }

    // ---- partial softmax over own 4 points ----
    float m = score[0];
#pragma unroll
    for (int p = 1; p < 4; ++p) m = fmaxf(m, score[p]);
    float sum = 0.f;
    float4 o = {0.f, 0.f, 0.f, 0.f};
#pragma unroll
    for (int p = 0; p < 4; ++p) {
        const float aw = __expf(score[p] - m);
        sum += aw;
        o.x += aw * sampled[p].x;
        o.y += aw * sampled[p].y;
        o.z += aw * sampled[p].z;
        o.w += aw * sampled[p].w;
    }

    // ---- merge with partner half (lane t^4): exact online-softmax merge ----
    const float m2   = __shfl_xor(m, 4);
    const float sum2 = __shfl_xor(sum, 4);
    float4 o2;
    o2.x = __shfl_xor(o.x, 4);
    o2.y = __shfl_xor(o.y, 4);
    o2.z = __shfl_xor(o.z, 4);
    o2.w = __shfl_xor(o.w, 4);
    const float mn = fmaxf(m, m2);
    const float sA = __expf(m - mn), sB = __expf(m2 - mn);
    const float tot = sum * sA + sum2 * sB;
    const float inv = 1.f / tot;
    o.x = (o.x * sA + o2.x * sB) * inv;
    o.y = (o.y * sA + o2.y * sB) * inv;
    o.z = (o.z * sA + o2.z * sB) * inv;
    o.w = (o.w * sA + o2.w * sB) * inv;

    if (ph == 0) {
        half4v hv = {(_Float16)o.x, (_Float16)o.y, (_Float16)o.z, (_Float16)o.w};
        *(half4v*)&att[((size_t)n * HW + s) * 128 + hd * 16 + d0] = hv;
    }
}

// ---------------------------------------------------------------------------
extern "C" void kernel_launch(void* const* d_in, const int* in_sizes, int n_in,
                              void* d_out, int out_size, void* d_ws, size_t ws_size,
                              hipStream_t stream) {
    const float* query = (const float*)d_in[0];
    const float* value = (const float*)d_in[1];
    const float* ref   = (const float*)d_in[2];
    const float* co_w1 = (const float*)d_in[3];
    const float* co_b1 = (const float*)d_in[4];
    const float* co_w2 = (const float*)d_in[5];
    const float* co_b2 = (const float*)d_in[6];
    const float* co_w3 = (const float*)d_in[7];
    const float* co_b3 = (const float*)d_in[8];
    const float* co_w4 = (const float*)d_in[9];
    const float* co_b4 = (const float*)d_in[10];
    const float* val_w = (const float*)d_in[11];
    const float* val_b = (const float*)d_in[12];
    const float* out_w = (const float*)d_in[13];
    const float* out_b = (const float*)d_in[14];

    char* ws = (char*)d_ws;
    size_t o = 0;
    auto alloc = [&](size_t bytes) { char* p = ws + o; o += (bytes + 255) & ~(size_t)255; return p; };

    _Float16* wb1 = (_Float16*)alloc(294912 * 2);   // de-aliased (round-12):
    _Float16* wb2 = (_Float16*)alloc(147456 * 2);   // conv1 and val-conv now independent
    _Float16* wb3 = (_Float16*)alloc(147456 * 2);
    _Float16* wb4 = (_Float16*)alloc(147456 * 2);
    _Float16* wbv = (_Float16*)alloc(16384 * 2);
    _Float16* wbo = (_Float16*)alloc(16384 * 2);
    float* v_s = (float*)alloc(3276800 * 4);        // v_s fp32 [32][6400][16]
    _Float16* v_h = (_Float16*)alloc((size_t)NB * HW * 128 * 2);  // 6.55 MB
    char* R1 = alloc((size_t)NB * 8 * PS * 32 * 2);  // 13.77 MB
    _Float16* q_h = (_Float16*)R1;             // fp16 planar [4][8][PS][32]
    float* o4 = (float*)R1;                    // fp32 NHWC [4][6400][128]; q_h dead
    char* R2 = alloc((size_t)NB * 4 * PS * 32 * 2 * 2);  // 13.78 MB
    _Float16* hA = (_Float16*)R2;              // fp16 planar [4][4][PS][32]
    _Float16* hB = (_Float16*)(R2 + (size_t)NB * 4 * PS * 32 * 2);
    _Float16* att_h = (_Float16*)R2;           // fp16 [4][6400][128]; hA dead by then

    // fused prep + transposes (independent work, block-range dispatch)
    prep_all<<<5104, 256, 0, stream>>>(co_w1, co_w2, co_w3, co_w4, val_w, out_w,
                                       wb1, wb2, wb3, wb4, wbv, wbo,
                                       (int*)q_h, (int*)hA, (int*)hB,
                                       query, value, q_h, v_h);

    // conv1 U val-conv (independent after wb1 de-alias): one launch
    conv1_val_fused<<<800, 256, 0, stream>>>(q_h, wb1, co_b1, hA,
                                             v_h, wbv, val_b, v_s);

    // rest of offset conv stack
    conv3x3_mfma<4, 1><<<400, 256, 0, stream>>>(hA, wb2, co_b2, hB);
    conv3x3_mfma<4, 1><<<400, 256, 0, stream>>>(hB, wb3, co_b3, hA);
    conv3x3_mfma<4, 2><<<400, 256, 0, stream>>>(hA, wb4, co_b4, o4);

    // deformable attention -> att_h (fp16 rows), XCD-pinned slices
    deform_attn_kernel<<<dim3(32, 200), 256, 0, stream>>>(v_s, o4, ref, att_h);

    // final 1x1 conv -> d_out (NCHW fp32)
    conv1x1_mfma<1><<<400, 256, 0, stream>>>(att_h, wbo, out_b, (float*)d_out);
}

// Round 13
// 216.748 us; speedup vs baseline: 1.0735x; 1.0041x over previous
//
#include <hip/hip_runtime.h>
#include <math.h>

#define Hh 80
#define Ww 80
#define HW 6400
#define PS 6724      // 82*82 padded spatial
#define NB 4

typedef _Float16 half8 __attribute__((ext_vector_type(8)));
typedef _Float16 half4v __attribute__((ext_vector_type(4)));
typedef float f32x16 __attribute__((ext_vector_type(16)));

// async global->LDS, 16B per lane. Dest is wave-uniform base (+lane*16 by HW);
// src is per-lane.
__device__ __forceinline__ void gload16(const _Float16* g, _Float16* l) {
    __builtin_amdgcn_global_load_lds(
        (const __attribute__((address_space(1))) void*)g,
        (__attribute__((address_space(3))) void*)l, 16, 0, 0);
}

// counted vmcnt wait (literal N) + full memory fence against code motion
#define WAITVM(N) asm volatile("s_waitcnt vmcnt(" #N ")" ::: "memory")
// issue-point pin: loads/stores cannot cross a memory clobber
#define FENCE() asm volatile("" ::: "memory")

__device__ __forceinline__ void barrier_mem() {
    asm volatile("" ::: "memory");
    __builtin_amdgcn_s_barrier();
    asm volatile("" ::: "memory");
}

// ---------------------------------------------------------------------------
// wblob helpers (weight-blob packing for MFMA A-operands)
// conv3x3 blob: flat = (CT*NS + c*18 + tap*2 + h)*512 + lane*8 + j
//   co = CT*32 + (lane&31);  ci = c*32 + h*16 + (lane>>5)*8 + j
// conv1x1 blob: flat = ((CT*8 + c)*64 + lane)*8 + j
//   co = CT*32 + (lane&31);  ci = c*16 + (lane>>5)*8 + j
// ---------------------------------------------------------------------------
__device__ inline void wblob_one(const float* src, _Float16* dst, int CI, int d) {
    int NC = CI / 32;
    int j = d & 7;
    int l = (d >> 3) & 63;
    int h = (d >> 9) & 1;
    int rest = d >> 10;
    int tap = rest % 9;
    rest /= 9;
    int c = rest % NC;
    int CT = rest / NC;
    int co = CT * 32 + (l & 31);
    int ci = c * 32 + h * 16 + (l >> 5) * 8 + j;
    dst[d] = (_Float16)src[((size_t)co * CI + ci) * 9 + tap];
}

__device__ inline void wblob1x1_one(const float* src, _Float16* dst, int d) {
    int j = d & 7;
    int l = (d >> 3) & 63;
    int c = (d >> 9) & 7;
    int CT = d >> 12;
    int co = CT * 32 + (l & 31);
    int ci = c * 16 + (l >> 5) * 8 + j;
    dst[d] = (_Float16)src[co * 128 + ci];
}

__device__ inline int padsite(int p) {
    if (p < 82) return p;                       // row 0
    if (p < 164) return 81 * 82 + (p - 82);     // row 81
    if (p < 244) return (p - 163) * 82;         // col 0, rows 1..80
    return (p - 243) * 82 + 81;                 // col 81, rows 1..80
}

// ---------------------------------------------------------------------------
// prep_all: fused {wblob prep + pad zeroing} U {q_transpose} U {v_transpose}.
// All three are mutually independent -> block-range dispatch, no interaction.
// b in [0,4304): prep; [4304,4704): q_transpose; [4704,5104): v_transpose.
// Both transpose offsets are multiples of 8 -> XCD pinning (b&7) preserved.
// (round-7 win: 3 launches -> 1, -4.6us)
// ---------------------------------------------------------------------------
__global__ __launch_bounds__(256) void prep_all(
    const float* __restrict__ w1, const float* __restrict__ w2,
    const float* __restrict__ w3, const float* __restrict__ w4,
    const float* __restrict__ vw, const float* __restrict__ ow,
    _Float16* __restrict__ b1, _Float16* __restrict__ b2,
    _Float16* __restrict__ b3, _Float16* __restrict__ b4,
    _Float16* __restrict__ bv, _Float16* __restrict__ bo,
    int* __restrict__ qh_i, int* __restrict__ hA_i, int* __restrict__ hB_i,
    const float* __restrict__ query, const float* __restrict__ value,
    _Float16* __restrict__ q_h, _Float16* __restrict__ v_h) {
    __shared__ _Float16 T[64 * 264];            // max(256+8, 128+8) stride tile
    const int blk = blockIdx.x;
    const int t = threadIdx.x;

    if (blk < 4304) {                           // ---- prep ----
        int idx = blk * 256 + t;
        if (idx < 294912) { wblob_one(w1, b1, 256, idx); return; }
        idx -= 294912;
        if (idx < 147456) { wblob_one(w2, b2, 128, idx); return; }
        idx -= 147456;
        if (idx < 147456) { wblob_one(w3, b3, 128, idx); return; }
        idx -= 147456;
        if (idx < 147456) { wblob_one(w4, b4, 128, idx); return; }
        idx -= 147456;
        if (idx < 16384) { wblob1x1_one(vw, bv, idx); return; }
        idx -= 16384;
        if (idx < 16384) { wblob1x1_one(ow, bo, idx); return; }
        idx -= 16384;
        if (idx < 165888) {  // q_h pads: 4n x 8c x 324 sites x 16 ints
            int n = idx / 41472, rr = idx % 41472;
            int c = rr / 5184, r2 = rr % 5184;
            int p = r2 >> 4, k = r2 & 15;
            qh_i[((size_t)(n * 8 + c) * PS + padsite(p)) * 16 + k] = 0;
            return;
        }
        idx -= 165888;
        if (idx < 82944) {   // hA pads
            int n = idx / 20736, rr = idx % 20736;
            int c = rr / 5184, r2 = rr % 5184;
            int p = r2 >> 4, k = r2 & 15;
            hA_i[((size_t)(n * 4 + c) * PS + padsite(p)) * 16 + k] = 0;
            return;
        }
        idx -= 82944;
        if (idx < 82944) {   // hB pads
            int n = idx / 20736, rr = idx % 20736;
            int c = rr / 5184, r2 = rr % 5184;
            int p = r2 >> 4, k = r2 & 15;
            hB_i[((size_t)(n * 4 + c) * PS + padsite(p)) * 16 + k] = 0;
        }
        return;
    }

    if (blk < 4704) {                           // ---- q_transpose ----
        const int b = blk - 4304;
        const int xcd = b & 7, n = xcd & 3, hi = xcd >> 2;
        const int s0 = hi * 3200 + (b >> 3) * 64;
        constexpr int CI = 256, ST = CI + 8;
        for (int idx = t; idx < 64 * CI; idx += 256) {
            int ci = idx >> 6, sl = idx & 63;
            T[sl * ST + ci] = (_Float16)query[((size_t)n * CI + ci) * HW + s0 + sl];
        }
        __syncthreads();
        for (int idx = t; idx < 64 * 32; idx += 256) {
            int q = idx & 31, sl = idx >> 5;
            int s = s0 + sl, yy = s / 80, xx = s % 80;
            int c = q >> 2, off = (q & 3) * 8;
            *(int4*)(q_h + ((size_t)(n * 8 + c) * PS + (yy + 1) * 82 + (xx + 1)) * 32 + off) =
                *(const int4*)(&T[sl * ST + q * 8]);
        }
        return;
    }

    {                                           // ---- v_transpose ----
        const int b = blk - 4704;
        const int xcd = b & 7, n = xcd & 3, hi = xcd >> 2;
        const int s0 = hi * 3200 + (b >> 3) * 64;
        constexpr int CI = 128, ST = CI + 8;
        for (int idx = t; idx < 64 * CI; idx += 256) {
            int ci = idx >> 6, sl = idx & 63;
            T[sl * ST + ci] = (_Float16)value[((size_t)n * CI + ci) * HW + s0 + sl];
        }
        __syncthreads();
        for (int idx = t; idx < 64 * 16; idx += 256) {
            int q = idx & 15, sl = idx >> 4;
            *(int4*)(v_h + ((size_t)n * HW + s0 + sl) * CI + q * 8) =
                *(const int4*)(&T[sl * ST + q * 8]);
        }
    }
}

// ---------------------------------------------------------------------------
// MFMA implicit-GEMM 3x3 conv body, v8 (PROVEN rounds 8/10/12).
// v6 geometry (4 waves x 1co x 2sp over 16x4 region, XCD-pinned, B dbuf in
// LDS via global_load_lds) with A (weights) in a PER-GROUP VGPR double-buffer
// (aA/aB, 6 x half8 = 24 VGPR each). Each group: {issue 6 A-loads; FENCE;
// compute 12 MFMA}. LDS 24 KB (B only), barriers 2/chunk at B-buffer flips
// with WAITVM(12). v5/v9 bracket this as the local optimum for this geometry.
// ACT 1: leaky -> chunked-planar fp16 [n][4c][PS][32].
// ACT 2: 10*tanh -> fp32 NHWC [n][6400][128].
// ---------------------------------------------------------------------------
template <int NCp, int ACT>
__device__ __forceinline__ void conv3x3_body(
    int b, const _Float16* __restrict__ in, const _Float16* __restrict__ wblob,
    const float* __restrict__ bias, void* __restrict__ outp) {
    constexpr int NS = NCp * 18;
    static_assert((NCp & 1) == 0, "pair loop needs even NCp");
    __shared__ _Float16 Bbuf[2][6 * 1024];   // 2 x 12KB (B only)

    const int xcd = b & 7, n = xcd & 3, hi = xcd >> 2;
    const int r = b >> 3;                    // 0..49: 16x4 region
    const int x0 = (r % 5) * 16, y0 = hi * 40 + (r / 5) * 4;
    const int t = threadIdx.x;
    const int w = t >> 6, l = t & 63;        // w = co-tile
    const int lane31 = l & 31, lhalf = l >> 5;
    const int lx = lane31 & 15, lyw = lane31 >> 4;
    const int si = l & 15, g8 = l >> 4;      // staging: site / granule of lane

    const _Float16* bplane0 = in + (size_t)(n * NCp) * PS * 32;
    const _Float16* wA = wblob + (size_t)w * NS * 512 + l * 8;   // per-lane A src

    f32x16 acc0 = {}, acc1 = {};
    half8 aA[6], aB[6];                      // per-group A register dbuf

    // stage B-tile (6 rows x 2 segs) of a chunk plane into Bbuf[par] (3 loads/wave)
    auto stageB = [&](const _Float16* plane, int par) {
#pragma unroll
        for (int j = 0; j < 3; ++j) {
            const int m = 3 * w + j, rr = m >> 1, sg = m & 1;
            gload16(plane + ((size_t)((y0 + rr) * 82 + x0 + sg * 16 + si)) * 32 + g8 * 8,
                    &Bbuf[par][rr * 1024 + sg * 512]);
        }
    };
    // load the 6 A-frags of 6-substep group grp into a register buffer
    auto loadA6 = [&](half8 (&ar)[6], int grp) {
        const _Float16* asrc = wA + (size_t)grp * 6 * 512;
#pragma unroll
        for (int k2 = 0; k2 < 6; ++k2)
            ar[k2] = *(const half8*)(asrc + (size_t)k2 * 512);
    };
    // compute the 6 substeps of sub-group gi from reg-A + LDS-B (12 MFMA)
    auto compute6 = [&](int gi, const half8 (&ar)[6], const _Float16* bb) {
#pragma unroll
        for (int k = 0; k < 6; ++k) {
            const int u = gi * 6 + k;            // compile-time after inline
            const int tap = u >> 1, h = u & 1;
            const int dy = tap / 3, dx = tap % 3;
            const int cx = lx + dx;
            const int boff = (cx >> 4) * 512 + (h * 2 + lhalf) * 128 + (cx & 15) * 8;
            half8 b0 = *(const half8*)&bb[(lyw + dy) * 1024 + boff];
            half8 b1 = *(const half8*)&bb[(lyw + 2 + dy) * 1024 + boff];
            acc0 = __builtin_amdgcn_mfma_f32_32x32x16_f16(ar[k], b0, acc0, 0, 0, 0);
            acc1 = __builtin_amdgcn_mfma_f32_32x32x16_f16(ar[k], b1, acc1, 0, 0, 0);
        }
    };

    // ---- prologue: B(chunk0) + A(group0), drained once ----
    stageB(bplane0, 0);
    loadA6(aA, 0);
    WAITVM(0);
    barrier_mem();

#pragma unroll 1
    for (int cp = 0; cp < NCp / 2; ++cp) {
        const int c0 = 2 * cp;
        const bool lastp = (cp == NCp / 2 - 1);
        const _Float16* plane1 = bplane0 + (size_t)(c0 + 1) * PS * 32;
        const _Float16* plane2 = bplane0 + (size_t)(c0 + 2) * PS * 32;
        // g0: issue A(c0,g1)+B(c1), pin, compute (c0,g0) from Bbuf0
        loadA6(aB, c0 * 3 + 1);
        stageB(plane1, 1);
        FENCE();
        compute6(0, aA, Bbuf[0]);
        // g1
        loadA6(aA, c0 * 3 + 2);
        FENCE();
        compute6(1, aB, Bbuf[0]);
        // g2: flip to Bbuf1 after this group
        loadA6(aB, c0 * 3 + 3);
        FENCE();
        compute6(2, aA, Bbuf[0]);
        WAITVM(12);          // B(c1) retired (12 loads issued after it)
        barrier_mem();       // all waves done reading Bbuf0; Bbuf1 visible
        // g3: stage next pair's even-chunk B into Bbuf0 (safe: post-barrier)
        loadA6(aA, c0 * 3 + 4);
        if (!lastp) stageB(plane2, 0);
        FENCE();
        compute6(0, aB, Bbuf[1]);
        // g4
        loadA6(aB, c0 * 3 + 5);
        FENCE();
        compute6(1, aA, Bbuf[1]);
        // g5: flip back to Bbuf0 (unless done)
        if (!lastp) {
            loadA6(aA, c0 * 3 + 6);
            FENCE();
            compute6(2, aB, Bbuf[1]);
            WAITVM(12);      // B(c0+2) retired (12 loads issued after it)
            barrier_mem();
        } else {
            FENCE();
            compute6(2, aB, Bbuf[1]);
        }
    }

    // epilogue: D col(site)=lane&31 -> (y=y0+lyw+2f, x=x0+lx);
    // row(co)=(reg&3)+8*(reg>>2)+4*(lane>>5)
    const int x = x0 + lx;
#pragma unroll
    for (int f = 0; f < 2; ++f) {
        const f32x16& acc = f ? acc1 : acc0;
        const int y = y0 + lyw + 2 * f;
#pragma unroll
        for (int q = 0; q < 4; ++q) {
            const int inner = 8 * q + 4 * lhalf;
            const int co0 = w * 32 + inner;
            float v[4];
#pragma unroll
            for (int i = 0; i < 4; ++i) {
                float vv = acc[q * 4 + i] + bias[co0 + i];
                if (ACT == 1) vv = (vv >= 0.f) ? vv : 0.1f * vv;
                else vv = 10.f * tanhf(vv);
                v[i] = vv;
            }
            if (ACT == 1) {
                half4v hv = {(_Float16)v[0], (_Float16)v[1], (_Float16)v[2], (_Float16)v[3]};
                *(half4v*)((_Float16*)outp +
                    ((size_t)(n * 4 + w) * PS + (y + 1) * 82 + (x + 1)) * 32 + inner) = hv;
            } else {
                float4 fv = {v[0], v[1], v[2], v[3]};
                *(float4*)((float*)outp + ((size_t)n * HW + y * 80 + x) * 128 + co0) = fv;
            }
        }
    }
}

template <int NCp, int ACT>
__global__ __launch_bounds__(256, 2) void conv3x3_mfma(
    const _Float16* __restrict__ in, const _Float16* __restrict__ wblob,
    const float* __restrict__ bias, void* __restrict__ outp) {
    conv3x3_body<NCp, ACT>(blockIdx.x, in, wblob, bias, outp);
}

// ---------------------------------------------------------------------------
// MFMA 1x1 conv body (K=128), fp16 rows [n][s][128] in, fp32 out.
// Barrier-free, XCD-pinned. Block 256 = 4 waves x 32 sites; wave = 64co.
// All 24 loads issued before the 16 MFMAs.
// MODE 0: out v_s fp32 [n*8+hd][s][16].
// ---------------------------------------------------------------------------
template <int MODE>
__device__ __forceinline__ void conv1x1_body(
    int b, const _Float16* __restrict__ in, const _Float16* __restrict__ wblob,
    const float* __restrict__ bias, float* __restrict__ outp) {
    const int xcd = b & 7, n = xcd & 3, hi = xcd >> 2;
    const int r = b >> 3;                    // 0..49
    const int coH = r & 1, strip = r >> 1;   // strip in [0,25)
    const int t = threadIdx.x;
    const int w = t >> 6, l = t & 63;
    const int lane31 = l & 31, lhalf = l >> 5;
    const int s = hi * 3200 + strip * 128 + w * 32 + lane31;

    const _Float16* pB = in + (size_t)(n * HW + s) * 128 + lhalf * 8;
    const _Float16* pA0 = wblob + (size_t)(coH * 2) * 8 * 512 + l * 8;
    const _Float16* pA1 = pA0 + 8 * 512;

    half8 bB[8], bA0[8], bA1[8];
#pragma unroll
    for (int c = 0; c < 8; ++c) {
        bB[c]  = *(const half8*)(pB + c * 16);
        bA0[c] = *(const half8*)(pA0 + (size_t)c * 512);
        bA1[c] = *(const half8*)(pA1 + (size_t)c * 512);
    }
    f32x16 acc0 = {}, acc1 = {};
#pragma unroll
    for (int c = 0; c < 8; ++c) {
        acc0 = __builtin_amdgcn_mfma_f32_32x32x16_f16(bA0[c], bB[c], acc0, 0, 0, 0);
        acc1 = __builtin_amdgcn_mfma_f32_32x32x16_f16(bA1[c], bB[c], acc1, 0, 0, 0);
    }

#pragma unroll
    for (int ct = 0; ct < 2; ++ct) {
        const f32x16& acc = ct ? acc1 : acc0;
#pragma unroll
        for (int q = 0; q < 4; ++q) {
            const int co0 = coH * 64 + ct * 32 + 8 * q + 4 * lhalf;
            if (MODE == 0) {
                const int hd = co0 >> 4, dd = co0 & 15;
                float4 fv = {acc[4 * q + 0] + bias[co0 + 0], acc[4 * q + 1] + bias[co0 + 1],
                             acc[4 * q + 2] + bias[co0 + 2], acc[4 * q + 3] + bias[co0 + 3]};
                *(float4*)&outp[((size_t)(n * 8 + hd) * HW + s) * 16 + dd] = fv;
            } else {
#pragma unroll
                for (int i = 0; i < 4; ++i)
                    outp[(size_t)(n * 128 + co0 + i) * HW + s] = acc[4 * q + i] + bias[co0 + i];
            }
        }
    }
}

// ---------------------------------------------------------------------------
// Fused conv1 (3x3, NCp=8, leaky) U val-conv (1x1, MODE 0): data-independent
// (wb1 de-aliased from v_s, round-12: -1.6us). Block-range dispatch:
// b in [0,400) -> conv1; [400,800) -> val-conv (400 % 8 == 0 preserves XCD
// pinning).
// ---------------------------------------------------------------------------
__global__ __launch_bounds__(256, 2) void conv1_val_fused(
    const _Float16* __restrict__ q_h, const _Float16* __restrict__ wb1,
    const float* __restrict__ co_b1, void* __restrict__ hA,
    const _Float16* __restrict__ v_h, const _Float16* __restrict__ wbv,
    const float* __restrict__ val_b, float* __restrict__ v_s) {
    const int b = blockIdx.x;
    if (b < 400) {
        conv3x3_body<8, 1>(b, q_h, wb1, co_b1, hA);
    } else {
        conv1x1_body<0>(b - 400, v_h, wbv, val_b, v_s);
    }
}

// ---------------------------------------------------------------------------
// Deformable attention v4 (round 13): deform + final 1x1 conv FUSED.
// Gather micro-structure identical to PROVEN v3 (point-pair split, 16
// parallel gathers/thread, partial softmax, exact pairwise shfl_xor merge).
// Restructure: block = 1024 thr = 16 sites x 8 heads x 8 subthreads; one
// WAVE = one site (64 lanes = 8hd x 8sub, so the existing shfl_xor(1/2/4)
// reductions stay intra-wave, same semantics). ph==0 lanes write fp16 att
// rows to a 16x136-stride LDS tile (2-way-free banks); one __syncthreads;
// waves 0..3 then run the 1x1 out-conv: 8 MFMAs each (A = wbo blob co-tile w,
// B = LDS att rows, c ascending -- SAME accumulation order as the old
// standalone conv1x1<1> -> bitwise-identical d_out). Cols 16..31 of the
// 32-site MFMA tile are discarded (lane31>=16 masked on store).
// Eliminates: att_h 13MB round trip + one launch (~7+2.3us); costs: ~2us
// epilogue + 1600-block tail. Occupancy during gathers unchanged: 16
// waves/CU (one 1024-thr block @ (1024,4), 128-VGPR cap = v3's budget).
// grid flat 1600, XCD-pinned: b&7 -> (n,hi); g=b>>3 in [0,200); s0=hi*3200+g*16.
// ---------------------------------------------------------------------------
__global__ __launch_bounds__(1024, 4) void deform_out_fused(
    const float* __restrict__ v_s, const float* __restrict__ offs,
    const float* __restrict__ ref, const _Float16* __restrict__ wbo,
    const float* __restrict__ out_b, float* __restrict__ outp) {
    __shared__ _Float16 attT[16 * 136];      // 16 sites x 128ch, stride 136
    const int b = blockIdx.x;
    const int xcd = b & 7, n = xcd & 3, hi = xcd >> 2;
    const int g = b >> 3;                    // 0..199
    const int s0 = hi * 3200 + g * 16;
    const int t = threadIdx.x;
    const int sub = t & 7, hd = (t >> 3) & 7, sl = t >> 6;   // sl: site 0..15
    const int s = s0 + sl;
    const int d0 = (sub & 3) * 4;
    const int ph = sub >> 2;                 // point half: points ph*4..ph*4+3
    const int nb = n * 8 + hd;
    const float* vbase = v_s + (size_t)nb * (HW * 16) + d0;

    const float4 cv = *(const float4*)&v_s[((size_t)nb * HW + s) * 16 + d0];
    const float rx = ref[(size_t)(n * HW + s) * 2 + 0] * 80.f - 0.5f;
    const float ry = ref[(size_t)(n * HW + s) * 2 + 1] * 80.f - 0.5f;

    const int e = (s >= 3200) ? 1 : 0;
    const float* ob0 = offs + ((size_t)n * HW + (2 * s - e * HW)) * 128 + hd * 16 + e;

    // ---- own half's offset loads (point q=ph*4+j: x at ob0[8ph+2j], y +128)
    float4 oxv0 = *(const float4*)(ob0 + 8 * ph);
    float4 oxv1 = *(const float4*)(ob0 + 8 * ph + 4);
    float4 oyv0 = *(const float4*)(ob0 + 128 + 8 * ph);
    float4 oyv1 = *(const float4*)(ob0 + 128 + 8 * ph + 4);
    float ox[4] = {oxv0.x, oxv0.z, oxv1.x, oxv1.z};
    float oy[4] = {oyv0.x, oyv0.z, oyv1.x, oyv1.z};

    // ---- coordinates/weights for own 4 points ----
    float wx1[4], wy1[4];
    int ix[4], iy[4];
#pragma unroll
    for (int p = 0; p < 4; ++p) {
        const float px = rx + ox[p];
        const float py = ry + oy[p];
        const float fx = floorf(px), fy = floorf(py);
        ix[p] = (int)fx; iy[p] = (int)fy;
        wx1[p] = px - fx; wy1[p] = py - fy;
    }

    // ---- all 16 gathers issued upfront (clamped, unconditional) ----
    float4 gg[4][4];
#pragma unroll
    for (int p = 0; p < 4; ++p) {
        const int xc0 = min(max(ix[p], 0), 79),     xc1 = min(max(ix[p] + 1, 0), 79);
        const int yc0 = min(max(iy[p], 0), 79),     yc1 = min(max(iy[p] + 1, 0), 79);
        const int r0 = yc0 * 80, r1 = yc1 * 80;
        gg[p][0] = *(const float4*)(vbase + (size_t)(r0 + xc0) * 16);
        gg[p][1] = *(const float4*)(vbase + (size_t)(r0 + xc1) * 16);
        gg[p][2] = *(const float4*)(vbase + (size_t)(r1 + xc0) * 16);
        gg[p][3] = *(const float4*)(vbase + (size_t)(r1 + xc1) * 16);
    }

    // ---- combine, score (reduce over d-groups: lanes t^1, t^2) ----
    float4 sampled[4];
    float score[4];
#pragma unroll
    for (int p = 0; p < 4; ++p) {
        const float vx0 = (ix[p] >= 0 && ix[p] < Ww) ? 1.f : 0.f;
        const float vx1 = (ix[p] + 1 >= 0 && ix[p] + 1 < Ww) ? 1.f : 0.f;
        const float vy0 = (iy[p] >= 0 && iy[p] < Hh) ? 1.f : 0.f;
        const float vy1 = (iy[p] + 1 >= 0 && iy[p] + 1 < Hh) ? 1.f : 0.f;
        const float wx0 = 1.f - wx1[p], wy0 = 1.f - wy1[p];
        const float w00 = wx0 * wy0 * vx0 * vy0;
        const float w01 = wx1[p] * wy0 * vx1 * vy0;
        const float w10 = wx0 * wy1[p] * vx0 * vy1;
        const float w11 = wx1[p] * wy1[p] * vx1 * vy1;
        float4 sv;
        sv.x = gg[p][0].x * w00 + gg[p][1].x * w01 + gg[p][2].x * w10 + gg[p][3].x * w11;
        sv.y = gg[p][0].y * w00 + gg[p][1].y * w01 + gg[p][2].y * w10 + gg[p][3].y * w11;
        sv.z = gg[p][0].z * w00 + gg[p][1].z * w01 + gg[p][2].z * w10 + gg[p][3].z * w11;
        sv.w = gg[p][0].w * w00 + gg[p][1].w * w01 + gg[p][2].w * w10 + gg[p][3].w * w11;
        sampled[p] = sv;
        float sc = sv.x * cv.x + sv.y * cv.y + sv.z * cv.z + sv.w * cv.w;
        sc += __shfl_xor(sc, 1);
        sc += __shfl_xor(sc, 2);
        score[p] = sc;
    }

    // ---- partial softmax over own 4 points ----
    float m = score[0];
#pragma unroll
    for (int p = 1; p < 4; ++p) m = fmaxf(m, score[p]);
    float sum = 0.f;
    float4 o = {0.f, 0.f, 0.f, 0.f};
#pragma unroll
    for (int p = 0; p < 4; ++p) {
        const float aw = __expf(score[p] - m);
        sum += aw;
        o.x += aw * sampled[p].x;
        o.y += aw * sampled[p].y;
        o.z += aw * sampled[p].z;
        o.w += aw * sampled[p].w;
    }

    // ---- merge with partner half (lane t^4): exact online-softmax merge ----
    const float m2   = __shfl_xor(m, 4);
    const float sum2 = __shfl_xor(sum, 4);
    float4 o2;
    o2.x = __shfl_xor(o.x, 4);
    o2.y = __shfl_xor(o.y, 4);
    o2.z = __shfl_xor(o.z, 4);
    o2.w = __shfl_xor(o.w, 4);
    const float mn = fmaxf(m, m2);
    const float sA = __expf(m - mn), sB = __expf(m2 - mn);
    const float tot = sum * sA + sum2 * sB;
    const float inv = 1.f / tot;
    o.x = (o.x * sA + o2.x * sB) * inv;
    o.y = (o.y * sA + o2.y * sB) * inv;
    o.z = (o.z * sA + o2.z * sB) * inv;
    o.w = (o.w * sA + o2.w * sB) * inv;

    if (ph == 0) {   // fp16 att row -> LDS (identical values to old att_h)
        half4v hv = {(_Float16)o.x, (_Float16)o.y, (_Float16)o.z, (_Float16)o.w};
        *(half4v*)&attT[sl * 136 + hd * 16 + d0] = hv;
    }
    __syncthreads();

    // ---- fused 1x1 out-conv: waves 0..3, co-tile w, 16 valid sites ----
    if (t < 256) {
        const int w = t >> 6, l = t & 63;
        const int lane31 = l & 31, lhalf = l >> 5;
        const int site = lane31 & 15;            // lanes 16..31 duplicate; masked
        const _Float16* pA = wbo + (size_t)w * 8 * 512 + l * 8;
        half8 bB[8], bA[8];
#pragma unroll
        for (int c = 0; c < 8; ++c) {
            bB[c] = *(const half8*)&attT[site * 136 + c * 16 + lhalf * 8];
            bA[c] = *(const half8*)(pA + (size_t)c * 512);
        }
        f32x16 acc = {};
#pragma unroll
        for (int c = 0; c < 8; ++c)
            acc = __builtin_amdgcn_mfma_f32_32x32x16_f16(bA[c], bB[c], acc, 0, 0, 0);
        if (lane31 < 16) {
#pragma unroll
            for (int q = 0; q < 4; ++q) {
                const int co0 = w * 32 + 8 * q + 4 * lhalf;
#pragma unroll
                for (int i = 0; i < 4; ++i)
                    outp[(size_t)(n * 128 + co0 + i) * HW + s0 + site] =
                        acc[4 * q + i] + out_b[co0 + i];
            }
        }
    }
}

// ---------------------------------------------------------------------------
extern "C" void kernel_launch(void* const* d_in, const int* in_sizes, int n_in,
                              void* d_out, int out_size, void* d_ws, size_t ws_size,
                              hipStream_t stream) {
    const float* query = (const float*)d_in[0];
    const float* value = (const float*)d_in[1];
    const float* ref   = (const float*)d_in[2];
    const float* co_w1 = (const float*)d_in[3];
    const float* co_b1 = (const float*)d_in[4];
    const float* co_w2 = (const float*)d_in[5];
    const float* co_b2 = (const float*)d_in[6];
    const float* co_w3 = (const float*)d_in[7];
    const float* co_b3 = (const float*)d_in[8];
    const float* co_w4 = (const float*)d_in[9];
    const float* co_b4 = (const float*)d_in[10];
    const float* val_w = (const float*)d_in[11];
    const float* val_b = (const float*)d_in[12];
    const float* out_w = (const float*)d_in[13];
    const float* out_b = (const float*)d_in[14];

    char* ws = (char*)d_ws;
    size_t o = 0;
    auto alloc = [&](size_t bytes) { char* p = ws + o; o += (bytes + 255) & ~(size_t)255; return p; };

    _Float16* wb1 = (_Float16*)alloc(294912 * 2);   // de-aliased (round-12)
    _Float16* wb2 = (_Float16*)alloc(147456 * 2);
    _Float16* wb3 = (_Float16*)alloc(147456 * 2);
    _Float16* wb4 = (_Float16*)alloc(147456 * 2);
    _Float16* wbv = (_Float16*)alloc(16384 * 2);
    _Float16* wbo = (_Float16*)alloc(16384 * 2);
    float* v_s = (float*)alloc(3276800 * 4);        // v_s fp32 [32][6400][16]
    _Float16* v_h = (_Float16*)alloc((size_t)NB * HW * 128 * 2);  // 6.55 MB
    char* R1 = alloc((size_t)NB * 8 * PS * 32 * 2);  // 13.77 MB
    _Float16* q_h = (_Float16*)R1;             // fp16 planar [4][8][PS][32]
    float* o4 = (float*)R1;                    // fp32 NHWC [4][6400][128]; q_h dead
    char* R2 = alloc((size_t)NB * 4 * PS * 32 * 2 * 2);  // 13.78 MB
    _Float16* hA = (_Float16*)R2;              // fp16 planar [4][4][PS][32]
    _Float16* hB = (_Float16*)(R2 + (size_t)NB * 4 * PS * 32 * 2);

    // fused prep + transposes (independent work, block-range dispatch)
    prep_all<<<5104, 256, 0, stream>>>(co_w1, co_w2, co_w3, co_w4, val_w, out_w,
                                       wb1, wb2, wb3, wb4, wbv, wbo,
                                       (int*)q_h, (int*)hA, (int*)hB,
                                       query, value, q_h, v_h);

    // conv1 U val-conv (independent): one launch
    conv1_val_fused<<<800, 256, 0, stream>>>(q_h, wb1, co_b1, hA,
                                             v_h, wbv, val_b, v_s);

    // rest of offset conv stack
    conv3x3_mfma<4, 1><<<400, 256, 0, stream>>>(hA, wb2, co_b2, hB);
    conv3x3_mfma<4, 1><<<400, 256, 0, stream>>>(hB, wb3, co_b3, hA);
    conv3x3_mfma<4, 2><<<400, 256, 0, stream>>>(hA, wb4, co_b4, o4);

    // deformable attention + final 1x1 conv fused -> d_out (NCHW fp32)
    deform_out_fused<<<1600, 1024, 0, stream>>>(v_s, o4, ref, wbo, out_b,
                                                (float*)d_out);
}

// Round 14
// 214.078 us; speedup vs baseline: 1.0869x; 1.0125x over previous
//
#include <hip/hip_runtime.h>
#include <math.h>

#define Hh 80
#define Ww 80
#define HW 6400
#define PS 6724      // 82*82 padded spatial
#define NB 4

typedef _Float16 half8 __attribute__((ext_vector_type(8)));
typedef _Float16 half4v __attribute__((ext_vector_type(4)));
typedef float f32x16 __attribute__((ext_vector_type(16)));

// async global->LDS, 16B per lane. Dest is wave-uniform base (+lane*16 by HW);
// src is per-lane.
__device__ __forceinline__ void gload16(const _Float16* g, _Float16* l) {
    __builtin_amdgcn_global_load_lds(
        (const __attribute__((address_space(1))) void*)g,
        (__attribute__((address_space(3))) void*)l, 16, 0, 0);
}

// counted vmcnt wait (literal N) + full memory fence against code motion
#define WAITVM(N) asm volatile("s_waitcnt vmcnt(" #N ")" ::: "memory")
// issue-point pin: loads/stores cannot cross a memory clobber
#define FENCE() asm volatile("" ::: "memory")

__device__ __forceinline__ void barrier_mem() {
    asm volatile("" ::: "memory");
    __builtin_amdgcn_s_barrier();
    asm volatile("" ::: "memory");
}

// ---------------------------------------------------------------------------
// Vectorized wblob helpers (round 14): one thread = one half8 (16B store).
// conv3x3 blob flat = (CT*NS + c*18 + tap*2 + h)*512 + lane*8 + j ->
// t8 = flat>>3 indexes (CT,c,tap,h,lane); the 8 j-sources are stride-9 floats
// (independent loads -> MLP). Byte-identical output to the old scalar path.
// ---------------------------------------------------------------------------
__device__ inline void wblob8(const float* src, _Float16* dst, int CI, int t8) {
    int NC = CI / 32;
    int l = t8 & 63;
    int h = (t8 >> 6) & 1;
    int rest = t8 >> 7;
    int tap = rest % 9;
    rest /= 9;
    int c = rest % NC;
    int CT = rest / NC;
    int co = CT * 32 + (l & 31);
    int cib = c * 32 + h * 16 + (l >> 5) * 8;
    const float* sp = src + ((size_t)co * CI + cib) * 9 + tap;
    half8 hv;
#pragma unroll
    for (int j = 0; j < 8; ++j) hv[j] = (_Float16)sp[j * 9];
    *(half8*)(dst + (size_t)t8 * 8) = hv;
}

__device__ inline void wblob1x1_8(const float* src, _Float16* dst, int t8) {
    int l = t8 & 63;
    int c = (t8 >> 6) & 7;
    int CT = t8 >> 9;
    int co = CT * 32 + (l & 31);
    int cib = c * 16 + (l >> 5) * 8;
    const float* sp = src + co * 128 + cib;   // 8 contiguous floats
    half8 hv;
#pragma unroll
    for (int j = 0; j < 8; ++j) hv[j] = (_Float16)sp[j];
    *(half8*)(dst + (size_t)t8 * 8) = hv;
}

__device__ inline int padsite(int p) {
    if (p < 82) return p;                       // row 0
    if (p < 164) return 81 * 82 + (p - 82);     // row 81
    if (p < 244) return (p - 163) * 82;         // col 0, rows 1..80
    return (p - 243) * 82 + 81;                 // col 81, rows 1..80
}

// ---------------------------------------------------------------------------
// prep_all v2 (round 14): vectorized 8x/4x. Prep threads 1.10M -> 179,200;
// grid 5104 -> 1504. Ranges: [0,704) prep (last 1024 idx idle);
// [704,1104) q_transpose; [1104,1504) v_transpose (both offsets % 8 == 0 ->
// XCD pinning preserved). Outputs byte-identical to the scalar version.
// Prep idx map: [0,36864) w1 | [36864,55296) w2 | [55296,73728) w3 |
// [73728,92160) w4 | [92160,94208) wbv | [94208,96256) wbo |
// [96256,137728) q_h pads int4 | [137728,158464) hA | [158464,179200) hB.
// ---------------------------------------------------------------------------
__global__ __launch_bounds__(256) void prep_all(
    const float* __restrict__ w1, const float* __restrict__ w2,
    const float* __restrict__ w3, const float* __restrict__ w4,
    const float* __restrict__ vw, const float* __restrict__ ow,
    _Float16* __restrict__ b1, _Float16* __restrict__ b2,
    _Float16* __restrict__ b3, _Float16* __restrict__ b4,
    _Float16* __restrict__ bv, _Float16* __restrict__ bo,
    int* __restrict__ qh_i, int* __restrict__ hA_i, int* __restrict__ hB_i,
    const float* __restrict__ query, const float* __restrict__ value,
    _Float16* __restrict__ q_h, _Float16* __restrict__ v_h) {
    __shared__ _Float16 T[64 * 264];            // max(256+8, 128+8) stride tile
    const int blk = blockIdx.x;
    const int t = threadIdx.x;

    if (blk < 704) {                            // ---- prep (vectorized) ----
        int idx = blk * 256 + t;
        if (idx < 36864) { wblob8(w1, b1, 256, idx); return; }
        idx -= 36864;
        if (idx < 18432) { wblob8(w2, b2, 128, idx); return; }
        idx -= 18432;
        if (idx < 18432) { wblob8(w3, b3, 128, idx); return; }
        idx -= 18432;
        if (idx < 18432) { wblob8(w4, b4, 128, idx); return; }
        idx -= 18432;
        if (idx < 2048) { wblob1x1_8(vw, bv, idx); return; }
        idx -= 2048;
        if (idx < 2048) { wblob1x1_8(ow, bo, idx); return; }
        idx -= 2048;
        const int4 z = {0, 0, 0, 0};
        if (idx < 41472) {   // q_h pads: [n(4)][c(8)][p(324)][kk(4)] int4
            int n = idx / 10368, rr = idx % 10368;
            int c = rr / 1296, r2 = rr % 1296;
            int p = r2 >> 2, kk = r2 & 3;
            *(int4*)&qh_i[((size_t)(n * 8 + c) * PS + padsite(p)) * 16 + kk * 4] = z;
            return;
        }
        idx -= 41472;
        if (idx < 20736) {   // hA pads: [n(4)][c(4)][p(324)][kk(4)]
            int n = idx / 5184, rr = idx % 5184;
            int c = rr / 1296, r2 = rr % 1296;
            int p = r2 >> 2, kk = r2 & 3;
            *(int4*)&hA_i[((size_t)(n * 4 + c) * PS + padsite(p)) * 16 + kk * 4] = z;
            return;
        }
        idx -= 20736;
        if (idx < 20736) {   // hB pads
            int n = idx / 5184, rr = idx % 5184;
            int c = rr / 1296, r2 = rr % 1296;
            int p = r2 >> 2, kk = r2 & 3;
            *(int4*)&hB_i[((size_t)(n * 4 + c) * PS + padsite(p)) * 16 + kk * 4] = z;
        }
        return;
    }

    if (blk < 1104) {                           // ---- q_transpose ----
        const int b = blk - 704;
        const int xcd = b & 7, n = xcd & 3, hi = xcd >> 2;
        const int s0 = hi * 3200 + (b >> 3) * 64;
        constexpr int CI = 256, ST = CI + 8;
        for (int idx = t; idx < 64 * CI; idx += 256) {
            int ci = idx >> 6, sl = idx & 63;
            T[sl * ST + ci] = (_Float16)query[((size_t)n * CI + ci) * HW + s0 + sl];
        }
        __syncthreads();
        for (int idx = t; idx < 64 * 32; idx += 256) {
            int q = idx & 31, sl = idx >> 5;
            int s = s0 + sl, yy = s / 80, xx = s % 80;
            int c = q >> 2, off = (q & 3) * 8;
            *(int4*)(q_h + ((size_t)(n * 8 + c) * PS + (yy + 1) * 82 + (xx + 1)) * 32 + off) =
                *(const int4*)(&T[sl * ST + q * 8]);
        }
        return;
    }

    {                                           // ---- v_transpose ----
        const int b = blk - 1104;
        const int xcd = b & 7, n = xcd & 3, hi = xcd >> 2;
        const int s0 = hi * 3200 + (b >> 3) * 64;
        constexpr int CI = 128, ST = CI + 8;
        for (int idx = t; idx < 64 * CI; idx += 256) {
            int ci = idx >> 6, sl = idx & 63;
            T[sl * ST + ci] = (_Float16)value[((size_t)n * CI + ci) * HW + s0 + sl];
        }
        __syncthreads();
        for (int idx = t; idx < 64 * 16; idx += 256) {
            int q = idx & 15, sl = idx >> 4;
            *(int4*)(v_h + ((size_t)n * HW + s0 + sl) * CI + q * 8) =
                *(const int4*)(&T[sl * ST + q * 8]);
        }
    }
}

// ---------------------------------------------------------------------------
// MFMA implicit-GEMM 3x3 conv body, v8 (PROVEN rounds 8/10/12/13).
// v6 geometry (4 waves x 1co x 2sp over 16x4 region, XCD-pinned, B dbuf in
// LDS via global_load_lds) with A (weights) in a PER-GROUP VGPR double-buffer
// (aA/aB, 6 x half8 = 24 VGPR each). Each group: {issue 6 A-loads; FENCE;
// compute 12 MFMA}. LDS 24 KB (B only), barriers 2/chunk at B-buffer flips
// with WAITVM(12). v5/v9 bracket this as the local optimum for this geometry.
// ACT 1: leaky -> chunked-planar fp16 [n][4c][PS][32].
// ACT 2: 10*tanh -> fp32 NHWC [n][6400][128].
// ---------------------------------------------------------------------------
template <int NCp, int ACT>
__device__ __forceinline__ void conv3x3_body(
    int b, const _Float16* __restrict__ in, const _Float16* __restrict__ wblob,
    const float* __restrict__ bias, void* __restrict__ outp) {
    constexpr int NS = NCp * 18;
    static_assert((NCp & 1) == 0, "pair loop needs even NCp");
    __shared__ _Float16 Bbuf[2][6 * 1024];   // 2 x 12KB (B only)

    const int xcd = b & 7, n = xcd & 3, hi = xcd >> 2;
    const int r = b >> 3;                    // 0..49: 16x4 region
    const int x0 = (r % 5) * 16, y0 = hi * 40 + (r / 5) * 4;
    const int t = threadIdx.x;
    const int w = t >> 6, l = t & 63;        // w = co-tile
    const int lane31 = l & 31, lhalf = l >> 5;
    const int lx = lane31 & 15, lyw = lane31 >> 4;
    const int si = l & 15, g8 = l >> 4;      // staging: site / granule of lane

    const _Float16* bplane0 = in + (size_t)(n * NCp) * PS * 32;
    const _Float16* wA = wblob + (size_t)w * NS * 512 + l * 8;   // per-lane A src

    f32x16 acc0 = {}, acc1 = {};
    half8 aA[6], aB[6];                      // per-group A register dbuf

    // stage B-tile (6 rows x 2 segs) of a chunk plane into Bbuf[par] (3 loads/wave)
    auto stageB = [&](const _Float16* plane, int par) {
#pragma unroll
        for (int j = 0; j < 3; ++j) {
            const int m = 3 * w + j, rr = m >> 1, sg = m & 1;
            gload16(plane + ((size_t)((y0 + rr) * 82 + x0 + sg * 16 + si)) * 32 + g8 * 8,
                    &Bbuf[par][rr * 1024 + sg * 512]);
        }
    };
    // load the 6 A-frags of 6-substep group grp into a register buffer
    auto loadA6 = [&](half8 (&ar)[6], int grp) {
        const _Float16* asrc = wA + (size_t)grp * 6 * 512;
#pragma unroll
        for (int k2 = 0; k2 < 6; ++k2)
            ar[k2] = *(const half8*)(asrc + (size_t)k2 * 512);
    };
    // compute the 6 substeps of sub-group gi from reg-A + LDS-B (12 MFMA)
    auto compute6 = [&](int gi, const half8 (&ar)[6], const _Float16* bb) {
#pragma unroll
        for (int k = 0; k < 6; ++k) {
            const int u = gi * 6 + k;            // compile-time after inline
            const int tap = u >> 1, h = u & 1;
            const int dy = tap / 3, dx = tap % 3;
            const int cx = lx + dx;
            const int boff = (cx >> 4) * 512 + (h * 2 + lhalf) * 128 + (cx & 15) * 8;
            half8 b0 = *(const half8*)&bb[(lyw + dy) * 1024 + boff];
            half8 b1 = *(const half8*)&bb[(lyw + 2 + dy) * 1024 + boff];
            acc0 = __builtin_amdgcn_mfma_f32_32x32x16_f16(ar[k], b0, acc0, 0, 0, 0);
            acc1 = __builtin_amdgcn_mfma_f32_32x32x16_f16(ar[k], b1, acc1, 0, 0, 0);
        }
    };

    // ---- prologue: B(chunk0) + A(group0), drained once ----
    stageB(bplane0, 0);
    loadA6(aA, 0);
    WAITVM(0);
    barrier_mem();

#pragma unroll 1
    for (int cp = 0; cp < NCp / 2; ++cp) {
        const int c0 = 2 * cp;
        const bool lastp = (cp == NCp / 2 - 1);
        const _Float16* plane1 = bplane0 + (size_t)(c0 + 1) * PS * 32;
        const _Float16* plane2 = bplane0 + (size_t)(c0 + 2) * PS * 32;
        // g0: issue A(c0,g1)+B(c1), pin, compute (c0,g0) from Bbuf0
        loadA6(aB, c0 * 3 + 1);
        stageB(plane1, 1);
        FENCE();
        compute6(0, aA, Bbuf[0]);
        // g1
        loadA6(aA, c0 * 3 + 2);
        FENCE();
        compute6(1, aB, Bbuf[0]);
        // g2: flip to Bbuf1 after this group
        loadA6(aB, c0 * 3 + 3);
        FENCE();
        compute6(2, aA, Bbuf[0]);
        WAITVM(12);          // B(c1) retired (12 loads issued after it)
        barrier_mem();       // all waves done reading Bbuf0; Bbuf1 visible
        // g3: stage next pair's even-chunk B into Bbuf0 (safe: post-barrier)
        loadA6(aA, c0 * 3 + 4);
        if (!lastp) stageB(plane2, 0);
        FENCE();
        compute6(0, aB, Bbuf[1]);
        // g4
        loadA6(aB, c0 * 3 + 5);
        FENCE();
        compute6(1, aA, Bbuf[1]);
        // g5: flip back to Bbuf0 (unless done)
        if (!lastp) {
            loadA6(aA, c0 * 3 + 6);
            FENCE();
            compute6(2, aB, Bbuf[1]);
            WAITVM(12);      // B(c0+2) retired (12 loads issued after it)
            barrier_mem();
        } else {
            FENCE();
            compute6(2, aB, Bbuf[1]);
        }
    }

    // epilogue: D col(site)=lane&31 -> (y=y0+lyw+2f, x=x0+lx);
    // row(co)=(reg&3)+8*(reg>>2)+4*(lane>>5)
    const int x = x0 + lx;
#pragma unroll
    for (int f = 0; f < 2; ++f) {
        const f32x16& acc = f ? acc1 : acc0;
        const int y = y0 + lyw + 2 * f;
#pragma unroll
        for (int q = 0; q < 4; ++q) {
            const int inner = 8 * q + 4 * lhalf;
            const int co0 = w * 32 + inner;
            float v[4];
#pragma unroll
            for (int i = 0; i < 4; ++i) {
                float vv = acc[q * 4 + i] + bias[co0 + i];
                if (ACT == 1) vv = (vv >= 0.f) ? vv : 0.1f * vv;
                else vv = 10.f * tanhf(vv);
                v[i] = vv;
            }
            if (ACT == 1) {
                half4v hv = {(_Float16)v[0], (_Float16)v[1], (_Float16)v[2], (_Float16)v[3]};
                *(half4v*)((_Float16*)outp +
                    ((size_t)(n * 4 + w) * PS + (y + 1) * 82 + (x + 1)) * 32 + inner) = hv;
            } else {
                float4 fv = {v[0], v[1], v[2], v[3]};
                *(float4*)((float*)outp + ((size_t)n * HW + y * 80 + x) * 128 + co0) = fv;
            }
        }
    }
}

template <int NCp, int ACT>
__global__ __launch_bounds__(256, 2) void conv3x3_mfma(
    const _Float16* __restrict__ in, const _Float16* __restrict__ wblob,
    const float* __restrict__ bias, void* __restrict__ outp) {
    conv3x3_body<NCp, ACT>(blockIdx.x, in, wblob, bias, outp);
}

// ---------------------------------------------------------------------------
// MFMA 1x1 conv body (K=128), fp16 rows [n][s][128] in, fp32 out.
// Barrier-free, XCD-pinned. Block 256 = 4 waves x 32 sites; wave = 64co.
// All 24 loads issued before the 16 MFMAs.
// MODE 0: out v_s fp32 [n*8+hd][s][16].
// ---------------------------------------------------------------------------
template <int MODE>
__device__ __forceinline__ void conv1x1_body(
    int b, const _Float16* __restrict__ in, const _Float16* __restrict__ wblob,
    const float* __restrict__ bias, float* __restrict__ outp) {
    const int xcd = b & 7, n = xcd & 3, hi = xcd >> 2;
    const int r = b >> 3;                    // 0..49
    const int coH = r & 1, strip = r >> 1;   // strip in [0,25)
    const int t = threadIdx.x;
    const int w = t >> 6, l = t & 63;
    const int lane31 = l & 31, lhalf = l >> 5;
    const int s = hi * 3200 + strip * 128 + w * 32 + lane31;

    const _Float16* pB = in + (size_t)(n * HW + s) * 128 + lhalf * 8;
    const _Float16* pA0 = wblob + (size_t)(coH * 2) * 8 * 512 + l * 8;
    const _Float16* pA1 = pA0 + 8 * 512;

    half8 bB[8], bA0[8], bA1[8];
#pragma unroll
    for (int c = 0; c < 8; ++c) {
        bB[c]  = *(const half8*)(pB + c * 16);
        bA0[c] = *(const half8*)(pA0 + (size_t)c * 512);
        bA1[c] = *(const half8*)(pA1 + (size_t)c * 512);
    }
    f32x16 acc0 = {}, acc1 = {};
#pragma unroll
    for (int c = 0; c < 8; ++c) {
        acc0 = __builtin_amdgcn_mfma_f32_32x32x16_f16(bA0[c], bB[c], acc0, 0, 0, 0);
        acc1 = __builtin_amdgcn_mfma_f32_32x32x16_f16(bA1[c], bB[c], acc1, 0, 0, 0);
    }

#pragma unroll
    for (int ct = 0; ct < 2; ++ct) {
        const f32x16& acc = ct ? acc1 : acc0;
#pragma unroll
        for (int q = 0; q < 4; ++q) {
            const int co0 = coH * 64 + ct * 32 + 8 * q + 4 * lhalf;
            if (MODE == 0) {
                const int hd = co0 >> 4, dd = co0 & 15;
                float4 fv = {acc[4 * q + 0] + bias[co0 + 0], acc[4 * q + 1] + bias[co0 + 1],
                             acc[4 * q + 2] + bias[co0 + 2], acc[4 * q + 3] + bias[co0 + 3]};
                *(float4*)&outp[((size_t)(n * 8 + hd) * HW + s) * 16 + dd] = fv;
            } else {
#pragma unroll
                for (int i = 0; i < 4; ++i)
                    outp[(size_t)(n * 128 + co0 + i) * HW + s] = acc[4 * q + i] + bias[co0 + i];
            }
        }
    }
}

// ---------------------------------------------------------------------------
// Fused conv1 (3x3, NCp=8, leaky) U val-conv (1x1, MODE 0): data-independent
// (wb1 de-aliased from v_s, round-12: -1.6us). Block-range dispatch:
// b in [0,400) -> conv1; [400,800) -> val-conv (400 % 8 == 0 preserves XCD
// pinning).
// ---------------------------------------------------------------------------
__global__ __launch_bounds__(256, 2) void conv1_val_fused(
    const _Float16* __restrict__ q_h, const _Float16* __restrict__ wb1,
    const float* __restrict__ co_b1, void* __restrict__ hA,
    const _Float16* __restrict__ v_h, const _Float16* __restrict__ wbv,
    const float* __restrict__ val_b, float* __restrict__ v_s) {
    const int b = blockIdx.x;
    if (b < 400) {
        conv3x3_body<8, 1>(b, q_h, wb1, co_b1, hA);
    } else {
        conv1x1_body<0>(b - 400, v_h, wbv, val_b, v_s);
    }
}

// ---------------------------------------------------------------------------
// Deformable attention v4 (PROVEN round 13: deform + final 1x1 conv fused).
// Gather micro-structure identical to v3 (point-pair split, 16 parallel
// gathers/thread, partial softmax, exact pairwise shfl_xor merge). Block =
// 1024 thr = 16 sites x 8 heads x 8 subthreads; one WAVE = one site. ph==0
// lanes write fp16 att rows to a 16x136 LDS tile; one __syncthreads; waves
// 0..3 run the 1x1 out-conv (8 MFMAs each, c ascending = same accumulation
// order as the old standalone conv -> bitwise-identical d_out).
// grid flat 1600, XCD-pinned.
// ---------------------------------------------------------------------------
__global__ __launch_bounds__(1024, 4) void deform_out_fused(
    const float* __restrict__ v_s, const float* __restrict__ offs,
    const float* __restrict__ ref, const _Float16* __restrict__ wbo,
    const float* __restrict__ out_b, float* __restrict__ outp) {
    __shared__ _Float16 attT[16 * 136];      // 16 sites x 128ch, stride 136
    const int b = blockIdx.x;
    const int xcd = b & 7, n = xcd & 3, hi = xcd >> 2;
    const int g = b >> 3;                    // 0..199
    const int s0 = hi * 3200 + g * 16;
    const int t = threadIdx.x;
    const int sub = t & 7, hd = (t >> 3) & 7, sl = t >> 6;   // sl: site 0..15
    const int s = s0 + sl;
    const int d0 = (sub & 3) * 4;
    const int ph = sub >> 2;                 // point half: points ph*4..ph*4+3
    const int nb = n * 8 + hd;
    const float* vbase = v_s + (size_t)nb * (HW * 16) + d0;

    const float4 cv = *(const float4*)&v_s[((size_t)nb * HW + s) * 16 + d0];
    const float rx = ref[(size_t)(n * HW + s) * 2 + 0] * 80.f - 0.5f;
    const float ry = ref[(size_t)(n * HW + s) * 2 + 1] * 80.f - 0.5f;

    const int e = (s >= 3200) ? 1 : 0;
    const float* ob0 = offs + ((size_t)n * HW + (2 * s - e * HW)) * 128 + hd * 16 + e;

    // ---- own half's offset loads (point q=ph*4+j: x at ob0[8ph+2j], y +128)
    float4 oxv0 = *(const float4*)(ob0 + 8 * ph);
    float4 oxv1 = *(const float4*)(ob0 + 8 * ph + 4);
    float4 oyv0 = *(const float4*)(ob0 + 128 + 8 * ph);
    float4 oyv1 = *(const float4*)(ob0 + 128 + 8 * ph + 4);
    float ox[4] = {oxv0.x, oxv0.z, oxv1.x, oxv1.z};
    float oy[4] = {oyv0.x, oyv0.z, oyv1.x, oyv1.z};

    // ---- coordinates/weights for own 4 points ----
    float wx1[4], wy1[4];
    int ix[4], iy[4];
#pragma unroll
    for (int p = 0; p < 4; ++p) {
        const float px = rx + ox[p];
        const float py = ry + oy[p];
        const float fx = floorf(px), fy = floorf(py);
        ix[p] = (int)fx; iy[p] = (int)fy;
        wx1[p] = px - fx; wy1[p] = py - fy;
    }

    // ---- all 16 gathers issued upfront (clamped, unconditional) ----
    float4 gg[4][4];
#pragma unroll
    for (int p = 0; p < 4; ++p) {
        const int xc0 = min(max(ix[p], 0), 79),     xc1 = min(max(ix[p] + 1, 0), 79);
        const int yc0 = min(max(iy[p], 0), 79),     yc1 = min(max(iy[p] + 1, 0), 79);
        const int r0 = yc0 * 80, r1 = yc1 * 80;
        gg[p][0] = *(const float4*)(vbase + (size_t)(r0 + xc0) * 16);
        gg[p][1] = *(const float4*)(vbase + (size_t)(r0 + xc1) * 16);
        gg[p][2] = *(const float4*)(vbase + (size_t)(r1 + xc0) * 16);
        gg[p][3] = *(const float4*)(vbase + (size_t)(r1 + xc1) * 16);
    }

    // ---- combine, score (reduce over d-groups: lanes t^1, t^2) ----
    float4 sampled[4];
    float score[4];
#pragma unroll
    for (int p = 0; p < 4; ++p) {
        const float vx0 = (ix[p] >= 0 && ix[p] < Ww) ? 1.f : 0.f;
        const float vx1 = (ix[p] + 1 >= 0 && ix[p] + 1 < Ww) ? 1.f : 0.f;
        const float vy0 = (iy[p] >= 0 && iy[p] < Hh) ? 1.f : 0.f;
        const float vy1 = (iy[p] + 1 >= 0 && iy[p] + 1 < Hh) ? 1.f : 0.f;
        const float wx0 = 1.f - wx1[p], wy0 = 1.f - wy1[p];
        const float w00 = wx0 * wy0 * vx0 * vy0;
        const float w01 = wx1[p] * wy0 * vx1 * vy0;
        const float w10 = wx0 * wy1[p] * vx0 * vy1;
        const float w11 = wx1[p] * wy1[p] * vx1 * vy1;
        float4 sv;
        sv.x = gg[p][0].x * w00 + gg[p][1].x * w01 + gg[p][2].x * w10 + gg[p][3].x * w11;
        sv.y = gg[p][0].y * w00 + gg[p][1].y * w01 + gg[p][2].y * w10 + gg[p][3].y * w11;
        sv.z = gg[p][0].z * w00 + gg[p][1].z * w01 + gg[p][2].z * w10 + gg[p][3].z * w11;
        sv.w = gg[p][0].w * w00 + gg[p][1].w * w01 + gg[p][2].w * w10 + gg[p][3].w * w11;
        sampled[p] = sv;
        float sc = sv.x * cv.x + sv.y * cv.y + sv.z * cv.z + sv.w * cv.w;
        sc += __shfl_xor(sc, 1);
        sc += __shfl_xor(sc, 2);
        score[p] = sc;
    }

    // ---- partial softmax over own 4 points ----
    float m = score[0];
#pragma unroll
    for (int p = 1; p < 4; ++p) m = fmaxf(m, score[p]);
    float sum = 0.f;
    float4 o = {0.f, 0.f, 0.f, 0.f};
#pragma unroll
    for (int p = 0; p < 4; ++p) {
        const float aw = __expf(score[p] - m);
        sum += aw;
        o.x += aw * sampled[p].x;
        o.y += aw * sampled[p].y;
        o.z += aw * sampled[p].z;
        o.w += aw * sampled[p].w;
    }

    // ---- merge with partner half (lane t^4): exact online-softmax merge ----
    const float m2   = __shfl_xor(m, 4);
    const float sum2 = __shfl_xor(sum, 4);
    float4 o2;
    o2.x = __shfl_xor(o.x, 4);
    o2.y = __shfl_xor(o.y, 4);
    o2.z = __shfl_xor(o.z, 4);
    o2.w = __shfl_xor(o.w, 4);
    const float mn = fmaxf(m, m2);
    const float sA = __expf(m - mn), sB = __expf(m2 - mn);
    const float tot = sum * sA + sum2 * sB;
    const float inv = 1.f / tot;
    o.x = (o.x * sA + o2.x * sB) * inv;
    o.y = (o.y * sA + o2.y * sB) * inv;
    o.z = (o.z * sA + o2.z * sB) * inv;
    o.w = (o.w * sA + o2.w * sB) * inv;

    if (ph == 0) {   // fp16 att row -> LDS (identical values to old att_h)
        half4v hv = {(_Float16)o.x, (_Float16)o.y, (_Float16)o.z, (_Float16)o.w};
        *(half4v*)&attT[sl * 136 + hd * 16 + d0] = hv;
    }
    __syncthreads();

    // ---- fused 1x1 out-conv: waves 0..3, co-tile w, 16 valid sites ----
    if (t < 256) {
        const int w = t >> 6, l = t & 63;
        const int lane31 = l & 31, lhalf = l >> 5;
        const int site = lane31 & 15;            // lanes 16..31 duplicate; masked
        const _Float16* pA = wbo + (size_t)w * 8 * 512 + l * 8;
        half8 bB[8], bA[8];
#pragma unroll
        for (int c = 0; c < 8; ++c) {
            bB[c] = *(const half8*)&attT[site * 136 + c * 16 + lhalf * 8];
            bA[c] = *(const half8*)(pA + (size_t)c * 512);
        }
        f32x16 acc = {};
#pragma unroll
        for (int c = 0; c < 8; ++c)
            acc = __builtin_amdgcn_mfma_f32_32x32x16_f16(bA[c], bB[c], acc, 0, 0, 0);
        if (lane31 < 16) {
#pragma unroll
            for (int q = 0; q < 4; ++q) {
                const int co0 = w * 32 + 8 * q + 4 * lhalf;
#pragma unroll
                for (int i = 0; i < 4; ++i)
                    outp[(size_t)(n * 128 + co0 + i) * HW + s0 + site] =
                        acc[4 * q + i] + out_b[co0 + i];
            }
        }
    }
}

// ---------------------------------------------------------------------------
extern "C" void kernel_launch(void* const* d_in, const int* in_sizes, int n_in,
                              void* d_out, int out_size, void* d_ws, size_t ws_size,
                              hipStream_t stream) {
    const float* query = (const float*)d_in[0];
    const float* value = (const float*)d_in[1];
    const float* ref   = (const float*)d_in[2];
    const float* co_w1 = (const float*)d_in[3];
    const float* co_b1 = (const float*)d_in[4];
    const float* co_w2 = (const float*)d_in[5];
    const float* co_b2 = (const float*)d_in[6];
    const float* co_w3 = (const float*)d_in[7];
    const float* co_b3 = (const float*)d_in[8];
    const float* co_w4 = (const float*)d_in[9];
    const float* co_b4 = (const float*)d_in[10];
    const float* val_w = (const float*)d_in[11];
    const float* val_b = (const float*)d_in[12];
    const float* out_w = (const float*)d_in[13];
    const float* out_b = (const float*)d_in[14];

    char* ws = (char*)d_ws;
    size_t o = 0;
    auto alloc = [&](size_t bytes) { char* p = ws + o; o += (bytes + 255) & ~(size_t)255; return p; };

    _Float16* wb1 = (_Float16*)alloc(294912 * 2);   // de-aliased (round-12)
    _Float16* wb2 = (_Float16*)alloc(147456 * 2);
    _Float16* wb3 = (_Float16*)alloc(147456 * 2);
    _Float16* wb4 = (_Float16*)alloc(147456 * 2);
    _Float16* wbv = (_Float16*)alloc(16384 * 2);
    _Float16* wbo = (_Float16*)alloc(16384 * 2);
    float* v_s = (float*)alloc(3276800 * 4);        // v_s fp32 [32][6400][16]
    _Float16* v_h = (_Float16*)alloc((size_t)NB * HW * 128 * 2);  // 6.55 MB
    char* R1 = alloc((size_t)NB * 8 * PS * 32 * 2);  // 13.77 MB
    _Float16* q_h = (_Float16*)R1;             // fp16 planar [4][8][PS][32]
    float* o4 = (float*)R1;                    // fp32 NHWC [4][6400][128]; q_h dead
    char* R2 = alloc((size_t)NB * 4 * PS * 32 * 2 * 2);  // 13.78 MB
    _Float16* hA = (_Float16*)R2;              // fp16 planar [4][4][PS][32]
    _Float16* hB = (_Float16*)(R2 + (size_t)NB * 4 * PS * 32 * 2);

    // fused prep + transposes (vectorized; independent work, block-range dispatch)
    prep_all<<<1504, 256, 0, stream>>>(co_w1, co_w2, co_w3, co_w4, val_w, out_w,
                                       wb1, wb2, wb3, wb4, wbv, wbo,
                                       (int*)q_h, (int*)hA, (int*)hB,
                                       query, value, q_h, v_h);

    // conv1 U val-conv (independent): one launch
    conv1_val_fused<<<800, 256, 0, stream>>>(q_h, wb1, co_b1, hA,
                                             v_h, wbv, val_b, v_s);

    // rest of offset conv stack
    conv3x3_mfma<4, 1><<<400, 256, 0, stream>>>(hA, wb2, co_b2, hB);
    conv3x3_mfma<4, 1><<<400, 256, 0, stream>>>(hB, wb3, co_b3, hA);
    conv3x3_mfma<4, 2><<<400, 256, 0, stream>>>(hA, wb4, co_b4, o4);

    // deformable attention + final 1x1 conv fused -> d_out (NCHW fp32)
    deform_out_fused<<<1600, 1024, 0, stream>>>(v_s, o4, ref, wbo, out_b,
                                                (float*)d_out);
}